// Round 5
// baseline (5065.630 us; speedup 1.0000x reference)
//
#include <hip/hip_runtime.h>
#include <hip/hip_bf16.h>

#define H_ 32
#define W_ 32
#define C_ 3
#define PH_ 5
#define PW_ 5
#define HP_ 28
#define WP_ 28
#define P_ 784
#define N_ 32
#define L_ 75
#define G_ 2
#define M_ 384
#define MM_ (M_*M_)       /* 147456 */
#define PN_ (P_*N_)       /* 25088 */
#define CHX_ 3136         /* x-chunk (PN_/8), multiple of 32 */
#define JITTER_ 1e-6

// accurate exp(t) for t <= 0, fp64
__device__ __forceinline__ double exp64(double t) {
  double y = t * 1.4426950408889634;
  double nn = rint(y);
  double z = (y - nn) * 0.6931471805599453;
  double e = 1.6059043836821613e-10;
  e = fma(e, z, 2.08767569878681e-9);
  e = fma(e, z, 2.505210838544172e-8);
  e = fma(e, z, 2.755731922398589e-7);
  e = fma(e, z, 2.7557319223985893e-6);
  e = fma(e, z, 2.48015873015873e-5);
  e = fma(e, z, 1.984126984126984e-4);
  e = fma(e, z, 1.3888888888888889e-3);
  e = fma(e, z, 8.333333333333333e-3);
  e = fma(e, z, 4.1666666666666664e-2);
  e = fma(e, z, 1.6666666666666666e-1);
  e = fma(e, z, 0.5);
  e = fma(e, z, 1.0);
  e = fma(e, z, 1.0);
  return ldexp(e, (int)nn);
}

// ---------------- Z transpose: Zt[(g*L+l)*M+m] = Z[(g*M+m)*L+l] ----------------
__global__ void k_zt(const float* __restrict__ Z, float* __restrict__ Zt) {
  int idx = blockIdx.x * 256 + threadIdx.x;
  if (idx >= G_ * L_ * M_) return;
  int m = idx % M_;
  int l = (idx / M_) % L_;
  int g = idx / (M_ * L_);
  Zt[idx] = Z[(g * M_ + m) * L_ + l];
}

// ---------------- Kuu fp32 (seed) ----------------
__global__ void k_kuu(const float* __restrict__ Z, const float* vptr,
                      const float* lptr, float* __restrict__ Kuu) {
  int idx = blockIdx.x * 256 + threadIdx.x;
  if (idx >= G_ * MM_) return;
  int j = idx % M_;
  int r = (idx / M_) % M_;
  int g = idx / MM_;
  const float* zi = Z + (g * M_ + r) * L_;
  const float* zj = Z + (g * M_ + j) * L_;
  float s = 0.f;
  for (int l = 0; l < L_; ++l) {
    float d = zi[l] - zj[l];
    s = fmaf(d, d, s);
  }
  float v = vptr[0], ls = lptr[0];
  float c2 = -0.72134752044f / (ls * ls);
  float val = v * exp2f(s * c2);
  if (r == j) val += (float)JITTER_;
  Kuu[idx] = val;
}

// ---------------- Kuu fp64 ----------------
__global__ void k_kuu64(const float* __restrict__ Z, const float* vptr,
                        const float* lptr, double* __restrict__ Kuu64) {
  int idx = blockIdx.x * 256 + threadIdx.x;
  if (idx >= G_ * MM_) return;
  int j = idx % M_;
  int r = (idx / M_) % M_;
  int g = idx / MM_;
  const float* zi = Z + (g * M_ + r) * L_;
  const float* zj = Z + (g * M_ + j) * L_;
  double s = 0.0;
  for (int l = 0; l < L_; ++l) {
    double d = (double)zi[l] - (double)zj[l];
    s = fma(d, d, s);
  }
  double v = (double)vptr[0], ls = (double)lptr[0];
  double val = v * exp64(-0.5 * s / (ls * ls));
  if (r == j) val += JITTER_;
  Kuu64[idx] = val;
}

// ---------------- register-resident 192x192 Gauss-Jordan inverse (SPD, fp32) ----------------
__global__ __launch_bounds__(512) void k_inv192(const float* __restrict__ in,
                                                float* __restrict__ out, int gstride) {
  int g = blockIdx.x;
  const float* A = in + (size_t)g * gstride;
  float* O = out + (size_t)g * gstride;
  int t = threadIdx.x;
  int ti = t >> 4, tj = t & 15;
  float a[6][12];
#pragma unroll
  for (int i2 = 0; i2 < 6; ++i2)
#pragma unroll
    for (int j2 = 0; j2 < 12; ++j2)
      a[i2][j2] = A[(ti + 32 * i2) * M_ + (tj + 16 * j2)];

  __shared__ float rowb[192], colb[192];
  for (int k = 0; k < 192; ++k) {
    if (ti == (k & 31)) {
      int i2k = k >> 5;
#pragma unroll
      for (int j2 = 0; j2 < 12; ++j2) rowb[tj + 16 * j2] = a[i2k][j2];
    }
    if (tj == (k & 15)) {
      int j2k = k >> 4;
#pragma unroll
      for (int i2 = 0; i2 < 6; ++i2) colb[ti + 32 * i2] = a[i2][j2k];
    }
    __syncthreads();
    float p = 1.0f / rowb[k];
    float rv[12];
#pragma unroll
    for (int j2 = 0; j2 < 12; ++j2) rv[j2] = rowb[tj + 16 * j2] * p;
    float cvl[6];
#pragma unroll
    for (int i2 = 0; i2 < 6; ++i2) cvl[i2] = colb[ti + 32 * i2];
#pragma unroll
    for (int i2 = 0; i2 < 6; ++i2)
#pragma unroll
      for (int j2 = 0; j2 < 12; ++j2)
        a[i2][j2] = fmaf(-cvl[i2], rv[j2], a[i2][j2]);
    if (ti == (k & 31)) {
      int i2k = k >> 5;
#pragma unroll
      for (int j2 = 0; j2 < 12; ++j2) a[i2k][j2] = rv[j2];
    }
    if (tj == (k & 15)) {
      int j2k = k >> 4;
#pragma unroll
      for (int i2 = 0; i2 < 6; ++i2) a[i2][j2k] = -cvl[i2] * p;
    }
    if (ti == (k & 31) && tj == (k & 15)) a[k >> 5][k >> 4] = p;
    __syncthreads();
  }
#pragma unroll
  for (int i2 = 0; i2 < 6; ++i2)
#pragma unroll
    for (int j2 = 0; j2 < 12; ++j2)
      O[(ti + 32 * i2) * M_ + (tj + 16 * j2)] = a[i2][j2];
}

// ---------------- fp32 tiled GEMM ----------------
__global__ __launch_bounds__(256) void k_sgemm(
    const float* __restrict__ A, int lda, int tA, int sAg,
    const float* __restrict__ B, int ldb, int tB, int sBg,
    const float* __restrict__ Cin, int sCing, float beta,
    float alpha,
    float* __restrict__ Cout, int ldc, int sCg,
    float* __restrict__ CoutT, int ldt, int sTg,
    int M, int N, int K) {
  int g = blockIdx.z;
  A += (size_t)g * sAg;
  B += (size_t)g * sBg;
  if (Cin) Cin += (size_t)g * sCing;
  Cout += (size_t)g * sCg;
  if (CoutT) CoutT += (size_t)g * sTg;

  __shared__ float As[32][33], Bs[32][33];
  int t = threadIdx.x;
  int tx = t & 15, ty = t >> 4;
  int row0 = blockIdx.y * 32, col0 = blockIdx.x * 32;
  float acc00 = 0.f, acc01 = 0.f, acc10 = 0.f, acc11 = 0.f;

  for (int kt = 0; kt < K; kt += 32) {
    for (int idx = t; idx < 1024; idx += 256) {
      int rr = idx >> 5, cc = idx & 31;
      {
        int gr = row0 + rr, gk = kt + cc;
        As[rr][cc] = tA ? A[(size_t)gk * lda + gr] : A[(size_t)gr * lda + gk];
      }
      {
        int gk = kt + rr, gc = col0 + cc;
        Bs[rr][cc] = tB ? B[(size_t)gc * ldb + gk] : B[(size_t)gk * ldb + gc];
      }
    }
    __syncthreads();
#pragma unroll
    for (int kk = 0; kk < 32; ++kk) {
      float a0 = As[ty * 2][kk], a1 = As[ty * 2 + 1][kk];
      float b0 = Bs[kk][tx * 2], b1 = Bs[kk][tx * 2 + 1];
      acc00 = fmaf(a0, b0, acc00);
      acc01 = fmaf(a0, b1, acc01);
      acc10 = fmaf(a1, b0, acc10);
      acc11 = fmaf(a1, b1, acc11);
    }
    __syncthreads();
  }
  float accs[2][2] = {{acc00, acc01}, {acc10, acc11}};
#pragma unroll
  for (int a2 = 0; a2 < 2; ++a2)
#pragma unroll
    for (int b2 = 0; b2 < 2; ++b2) {
      int gr = row0 + ty * 2 + a2, gc = col0 + tx * 2 + b2;
      float val = alpha * accs[a2][b2];
      if (Cin) val += beta * Cin[(size_t)gr * ldc + gc];
      Cout[(size_t)gr * ldc + gc] = val;
      if (CoutT) CoutT[(size_t)gc * ldt + gr] = val;
    }
}

// ---------------- fp64 tiled GEMM: Cout = alpha*op(A)*op(B) [+ I] [+ beta*Cin] ----------------
__global__ __launch_bounds__(256) void k_dgemm(
    const double* __restrict__ A, int lda, int tA, int sAg,
    const double* __restrict__ B, int ldb, int tB, int sBg,
    const double* __restrict__ Cin, int sCing, double beta,
    double alpha, int addI,
    double* __restrict__ Cout, int ldc, int sCg,
    float* __restrict__ f32out,
    int M, int N, int K) {
  int g = blockIdx.z;
  A += (size_t)g * sAg;
  B += (size_t)g * sBg;
  if (Cin) Cin += (size_t)g * sCing;
  Cout += (size_t)g * sCg;
  if (f32out) f32out += (size_t)g * sCg;

  __shared__ double As[32][33], Bs[32][33];
  int t = threadIdx.x;
  int tx = t & 15, ty = t >> 4;
  int row0 = blockIdx.y * 32, col0 = blockIdx.x * 32;
  double acc00 = 0., acc01 = 0., acc10 = 0., acc11 = 0.;

  for (int kt = 0; kt < K; kt += 32) {
    for (int idx = t; idx < 1024; idx += 256) {
      int rr = idx >> 5, cc = idx & 31;
      {
        int gr = row0 + rr, gk = kt + cc;
        As[rr][cc] = tA ? A[(size_t)gk * lda + gr] : A[(size_t)gr * lda + gk];
      }
      {
        int gk = kt + rr, gc = col0 + cc;
        Bs[rr][cc] = tB ? B[(size_t)gc * ldb + gk] : B[(size_t)gk * ldb + gc];
      }
    }
    __syncthreads();
#pragma unroll
    for (int kk = 0; kk < 32; ++kk) {
      double a0 = As[ty * 2][kk], a1 = As[ty * 2 + 1][kk];
      double b0 = Bs[kk][tx * 2], b1 = Bs[kk][tx * 2 + 1];
      acc00 = fma(a0, b0, acc00);
      acc01 = fma(a0, b1, acc01);
      acc10 = fma(a1, b0, acc10);
      acc11 = fma(a1, b1, acc11);
    }
    __syncthreads();
  }
  double accs[2][2] = {{acc00, acc01}, {acc10, acc11}};
#pragma unroll
  for (int a2 = 0; a2 < 2; ++a2)
#pragma unroll
    for (int b2 = 0; b2 < 2; ++b2) {
      int gr = row0 + ty * 2 + a2, gc = col0 + tx * 2 + b2;
      double val = alpha * accs[a2][b2];
      if (addI && gr == gc) val += 1.0;
      if (Cin) val += beta * Cin[(size_t)gr * ldc + gc];
      Cout[(size_t)gr * ldc + gc] = val;
      if (f32out) f32out[(size_t)gr * ldc + gc] = (float)val;
    }
}

// ---------------- small helpers ----------------
__global__ void k_f2d(const float* __restrict__ in, double* __restrict__ out, int n) {
  int idx = blockIdx.x * 256 + threadIdx.x;
  if (idx < n) out[idx] = (double)in[idx];
}

__global__ void k_prep_lq(const float* __restrict__ qsqrt, double* __restrict__ Lq64) {
  int idx = blockIdx.x * 256 + threadIdx.x;
  if (idx >= G_ * MM_) return;
  int col = idx % M_;
  int row = (idx / M_) % M_;
  Lq64[idx] = (col <= row) ? (double)qsqrt[idx] : 0.0;
}

// c_g = X * q_mu[:,g] in fp64, output fp32
__global__ void k_cvec64(const double* __restrict__ X, const float* __restrict__ qmu,
                         float* __restrict__ cvec) {
  int idx = blockIdx.x * 256 + threadIdx.x;
  if (idx >= G_ * M_) return;
  int m = idx % M_, g = idx / M_;
  const double* row = X + (size_t)g * MM_ + (size_t)m * M_;
  double s = 0.0;
  for (int k = 0; k < M_; ++k) s = fma(row[k], (double)qmu[k * G_ + g], s);
  cvec[idx] = (float)s;
}

// ---------------- Kx[g][xl][m] = rbf(Z[g,m], patch(x)), x = x0 + blockIdx.x ----------------
__global__ __launch_bounds__(384) void k_kuf(const float* __restrict__ xin,
                                             const float* __restrict__ Zt,
                                             const float* vptr, const float* lptr,
                                             float* __restrict__ Kx, int x0) {
  int xl = blockIdx.x;           // local chunk index
  int x = x0 + xl;               // global column: x = p*N + n
  int g = blockIdx.y;
  int m = threadIdx.x;
  int p = x / N_, n = x % N_;
  int hp = p / WP_, wp = p % WP_;
  __shared__ float pt[L_];
  if (m < L_) {
    int q = m / C_, c = m % C_;
    int i = q / PW_, j = q % PW_;
    pt[m] = xin[n * (H_ * W_ * C_) + ((hp + i) * W_ + (wp + j)) * C_ + c];
  }
  __syncthreads();
  float s = 0.f;
  for (int l = 0; l < L_; ++l) {
    float d = Zt[(g * L_ + l) * M_ + m] - pt[l];
    s = fmaf(d, d, s);
  }
  float v = vptr[0], ls = lptr[0];
  float c2 = -0.72134752044f / (ls * ls);
  Kx[((size_t)g * CHX_ + xl) * M_ + m] = v * exp2f(s * c2);
}

// ---------------- fold: one wave per x. mean = k.c ; var = v + k.u (fp64 accum) ----------------
__global__ __launch_bounds__(256) void k_fold(const float* __restrict__ Kx,
                                              const float* __restrict__ U,
                                              const float* __restrict__ cvec,
                                              const float* vptr,
                                              float* __restrict__ outp, int x0) {
  int g = blockIdx.y;
  int wv = threadIdx.x >> 6, lane = threadIdx.x & 63;
  int xl = blockIdx.x * 4 + wv;      // < CHX_
  int x = x0 + xl;
  const float* krow = Kx + ((size_t)g * CHX_ + xl) * M_;
  const float* urow = U + ((size_t)g * CHX_ + xl) * M_;
  const float* cg = cvec + g * M_;
  double fv = 0.0, fm = 0.0;
  for (int m = lane; m < M_; m += 64) {
    double kk = (double)krow[m];
    fv = fma(kk, (double)urow[m], fv);
    fm = fma(kk, (double)cg[m], fm);
  }
#pragma unroll
  for (int off = 32; off; off >>= 1) {
    fv += __shfl_down(fv, off);
    fm += __shfl_down(fm, off);
  }
  if (lane == 0) {
    int p = x / N_, n = x % N_;
    int oidx = n * (P_ * G_) + p * G_ + g;
    outp[oidx] = (float)fm;
    outp[PN_ * G_ + oidx] = (float)((double)vptr[0] + fv);
  }
}

extern "C" void kernel_launch(void* const* d_in, const int* in_sizes, int n_in,
                              void* d_out, int out_size, void* d_ws, size_t ws_size,
                              hipStream_t stream) {
  (void)out_size; (void)ws_size;
  // defensive size-based input mapping (dict order expected, verify by flat sizes)
  const float* xin = (const float*)d_in[0];
  const float* Z = (const float*)d_in[1];
  const float* qmu = (const float*)d_in[2];
  const float* qsqrt = (const float*)d_in[3];
  const float* vptr = (const float*)d_in[4];
  const float* lptr = (const float*)d_in[5];
  {
    int scalars = 0;
    for (int i = 0; i < n_in; ++i) {
      if (in_sizes[i] == N_ * H_ * W_ * C_) xin = (const float*)d_in[i];
      else if (in_sizes[i] == G_ * M_ * L_) Z = (const float*)d_in[i];
      else if (in_sizes[i] == M_ * G_) qmu = (const float*)d_in[i];
      else if (in_sizes[i] == G_ * MM_) qsqrt = (const float*)d_in[i];
      else if (in_sizes[i] == 1) {
        if (scalars == 0) vptr = (const float*)d_in[i];
        else lptr = (const float*)d_in[i];
        ++scalars;
      }
    }
  }
  float* outp = (float*)d_out;   // fp32 output (reference outputs are float32)

  char* w = (char*)d_ws;
  auto alloc = [&](size_t bytes) {
    char* r = w;
    w += (bytes + 255) & ~(size_t)255;
    return r;
  };
  float* Zt     = (float*)alloc((size_t)G_ * L_ * M_ * 4);
  float* Kuu32  = (float*)alloc((size_t)G_ * MM_ * 4);
  float* Kinv32 = (float*)alloc((size_t)G_ * MM_ * 4);
  float* Ebuf   = (float*)alloc((size_t)G_ * 192 * 192 * 4);
  double* Kuu64 = (double*)alloc((size_t)G_ * MM_ * 8);
  double* Xd    = (double*)alloc((size_t)G_ * MM_ * 8);
  double* Xd2   = (double*)alloc((size_t)G_ * MM_ * 8);
  double* Rd    = (double*)alloc((size_t)G_ * MM_ * 8);
  double* Lq64  = (double*)alloc((size_t)G_ * MM_ * 8);
  double* V64   = (double*)alloc((size_t)G_ * MM_ * 8);
  float* Sf     = (float*)alloc((size_t)G_ * MM_ * 4);
  float* cvec   = (float*)alloc((size_t)G_ * M_ * 4);
  float* Kx     = (float*)alloc((size_t)G_ * CHX_ * M_ * 4);
  float* U      = (float*)alloc((size_t)G_ * CHX_ * M_ * 4);

  k_zt<<<(G_ * L_ * M_ + 255) / 256, 256, 0, stream>>>(Z, Zt);
  k_kuu<<<(G_ * MM_ + 255) / 256, 256, 0, stream>>>(Z, vptr, lptr, Kuu32);
  k_kuu64<<<(G_ * MM_ + 255) / 256, 256, 0, stream>>>(Z, vptr, lptr, Kuu64);

  // ---- fp32 seed: Kinv32 via 2x2 block Schur (192+192) ----
  k_inv192<<<G_, 512, 0, stream>>>(Kuu32, Kinv32, MM_);
  k_sgemm<<<dim3(6, 6, G_), 256, 0, stream>>>(
      Kinv32, M_, 0, MM_,
      Kuu32 + 192, M_, 0, MM_,
      nullptr, 0, 0.0f, 1.0f,
      Ebuf, 192, 192 * 192, nullptr, 0, 0, 192, 192, 192);
  k_sgemm<<<dim3(6, 6, G_), 256, 0, stream>>>(
      Kuu32 + 192, M_, 1, MM_,
      Ebuf, 192, 0, 192 * 192,
      Kuu32 + 192 * M_ + 192, MM_, 1.0f, -1.0f,
      Kuu32 + 192 * M_ + 192, M_, MM_, nullptr, 0, 0, 192, 192, 192);
  k_inv192<<<G_, 512, 0, stream>>>(Kuu32 + 192 * M_ + 192, Kinv32 + 192 * M_ + 192, MM_);
  k_sgemm<<<dim3(6, 6, G_), 256, 0, stream>>>(
      Ebuf, 192, 0, 192 * 192,
      Kinv32 + 192 * M_ + 192, M_, 0, MM_,
      nullptr, 0, 0.0f, -1.0f,
      Kinv32 + 192, M_, MM_, Kinv32 + 192 * M_, M_, MM_, 192, 192, 192);
  k_sgemm<<<dim3(6, 6, G_), 256, 0, stream>>>(
      Kinv32 + 192, M_, 0, MM_,
      Ebuf, 192, 1, 192 * 192,
      Kinv32, MM_, 1.0f, -1.0f,
      Kinv32, M_, MM_, nullptr, 0, 0, 192, 192, 192);

  // ---- Newton polish in fp64: X <- X + X(I - Kuu X), twice ----
  k_f2d<<<(G_ * MM_ + 255) / 256, 256, 0, stream>>>(Kinv32, Xd, G_ * MM_);
  k_dgemm<<<dim3(12, 12, G_), 256, 0, stream>>>(
      Kuu64, M_, 0, MM_, Xd, M_, 0, MM_,
      nullptr, 0, 0.0, -1.0, 1, Rd, M_, MM_, nullptr, M_, M_, M_);
  k_dgemm<<<dim3(12, 12, G_), 256, 0, stream>>>(
      Xd, M_, 0, MM_, Rd, M_, 0, MM_,
      Xd, MM_, 1.0, 1.0, 0, Xd2, M_, MM_, nullptr, M_, M_, M_);
  k_dgemm<<<dim3(12, 12, G_), 256, 0, stream>>>(
      Kuu64, M_, 0, MM_, Xd2, M_, 0, MM_,
      nullptr, 0, 0.0, -1.0, 1, Rd, M_, MM_, nullptr, M_, M_, M_);
  k_dgemm<<<dim3(12, 12, G_), 256, 0, stream>>>(
      Xd2, M_, 0, MM_, Rd, M_, 0, MM_,
      Xd2, MM_, 1.0, 1.0, 0, Xd, M_, MM_, nullptr, M_, M_, M_);

  // ---- S = (X Lq)(X Lq)^T - X in fp64 -> Sf fp32 (Rd reused as fp64 out) ----
  k_prep_lq<<<(G_ * MM_ + 255) / 256, 256, 0, stream>>>(qsqrt, Lq64);
  k_dgemm<<<dim3(12, 12, G_), 256, 0, stream>>>(
      Xd, M_, 0, MM_, Lq64, M_, 0, MM_,
      nullptr, 0, 0.0, 1.0, 0, V64, M_, MM_, nullptr, M_, M_, M_);
  k_dgemm<<<dim3(12, 12, G_), 256, 0, stream>>>(
      V64, M_, 0, MM_, V64, M_, 1, MM_,
      Xd, MM_, -1.0, 1.0, 0, Rd, M_, MM_, Sf, M_, M_, M_);

  // ---- c = X q_mu ----
  k_cvec64<<<3, 256, 0, stream>>>(Xd, qmu, cvec);

  // ---- per-chunk: K build (direct from inputs), U = K*S, fold to outputs ----
  for (int ch = 0; ch < PN_ / CHX_; ++ch) {
    int x0 = ch * CHX_;
    k_kuf<<<dim3(CHX_, G_), 384, 0, stream>>>(xin, Zt, vptr, lptr, Kx, x0);
    k_sgemm<<<dim3(M_ / 32, CHX_ / 32, G_), 256, 0, stream>>>(
        Kx, M_, 0, CHX_ * M_,
        Sf, M_, 0, MM_,
        nullptr, 0, 0.0f, 1.0f,
        U, M_, CHX_ * M_, nullptr, 0, 0, CHX_, M_, M_);
    k_fold<<<dim3(CHX_ / 4, G_), 256, 0, stream>>>(Kx, U, cvec, vptr, outp, x0);
  }
}

// Round 6
// 1175.680 us; speedup vs baseline: 4.3087x; 4.3087x over previous
//
#include <hip/hip_runtime.h>
#include <hip/hip_bf16.h>

#define H_ 32
#define W_ 32
#define C_ 3
#define PH_ 5
#define PW_ 5
#define HP_ 28
#define WP_ 28
#define P_ 784
#define N_ 32
#define L_ 75
#define G_ 2
#define M_ 384
#define MM_ (M_*M_)       /* 147456 */
#define PN_ (P_*N_)       /* 25088 */
#define CHX_ 3136         /* x-chunk (PN_/8) */
#define JITTER_ 1e-6

// accurate exp(t) for t <= 0, fp64
__device__ __forceinline__ double exp64(double t) {
  double y = t * 1.4426950408889634;
  double nn = rint(y);
  double z = (y - nn) * 0.6931471805599453;
  double e = 1.6059043836821613e-10;
  e = fma(e, z, 2.08767569878681e-9);
  e = fma(e, z, 2.505210838544172e-8);
  e = fma(e, z, 2.755731922398589e-7);
  e = fma(e, z, 2.7557319223985893e-6);
  e = fma(e, z, 2.48015873015873e-5);
  e = fma(e, z, 1.984126984126984e-4);
  e = fma(e, z, 1.3888888888888889e-3);
  e = fma(e, z, 8.333333333333333e-3);
  e = fma(e, z, 4.1666666666666664e-2);
  e = fma(e, z, 1.6666666666666666e-1);
  e = fma(e, z, 0.5);
  e = fma(e, z, 1.0);
  e = fma(e, z, 1.0);
  return ldexp(e, (int)nn);
}

// ---------------- Z transpose: Zt[(g*L+l)*M+m] = Z[(g*M+m)*L+l] ----------------
__global__ void k_zt(const float* __restrict__ Z, float* __restrict__ Zt) {
  int idx = blockIdx.x * 256 + threadIdx.x;
  if (idx >= G_ * L_ * M_) return;
  int m = idx % M_;
  int l = (idx / M_) % L_;
  int g = idx / (M_ * L_);
  Zt[idx] = Z[(g * M_ + m) * L_ + l];
}

// ---------------- Kuu fp64 ----------------
__global__ void k_kuu64(const float* __restrict__ Z, const float* vptr,
                        const float* lptr, double* __restrict__ Kuu64) {
  int idx = blockIdx.x * 256 + threadIdx.x;
  if (idx >= G_ * MM_) return;
  int j = idx % M_;
  int r = (idx / M_) % M_;
  int g = idx / MM_;
  const float* zi = Z + (g * M_ + r) * L_;
  const float* zj = Z + (g * M_ + j) * L_;
  double s = 0.0;
  for (int l = 0; l < L_; ++l) {
    double d = (double)zi[l] - (double)zj[l];
    s = fma(d, d, s);
  }
  double v = (double)vptr[0], ls = (double)lptr[0];
  double val = v * exp64(-0.5 * s / (ls * ls));
  if (r == j) val += JITTER_;
  Kuu64[idx] = val;
}

// ---------------- casts ----------------
__global__ void k_d2f(const double* __restrict__ in, float* __restrict__ out, int n) {
  int idx = blockIdx.x * 256 + threadIdx.x;
  if (idx < n) out[idx] = (float)in[idx];
}
__global__ void k_f2d(const float* __restrict__ in, double* __restrict__ out, int n) {
  int idx = blockIdx.x * 256 + threadIdx.x;
  if (idx < n) out[idx] = (double)in[idx];
}

// ---------------- register-resident 192x192 Gauss-Jordan inverse (SPD, fp32) ----------------
// All register-array indices are COMPILE-TIME (k split as i2k*32 + kh*16 + k2)
// to avoid scratch-spill of a[6][12]. grid=G, block=512: ti=t>>4 (0..31), tj=t&15.
// rows r = ti + 32*i2 (i2<6), cols c = tj + 16*j2 (j2<12)
__global__ __launch_bounds__(512) void k_inv192(const float* __restrict__ in,
                                                float* __restrict__ out, int gstride) {
  int g = blockIdx.x;
  const float* A = in + (size_t)g * gstride;
  float* O = out + (size_t)g * gstride;
  int t = threadIdx.x;
  int ti = t >> 4, tj = t & 15;
  float a[6][12];
#pragma unroll
  for (int i2 = 0; i2 < 6; ++i2)
#pragma unroll
    for (int j2 = 0; j2 < 12; ++j2)
      a[i2][j2] = A[(ti + 32 * i2) * M_ + (tj + 16 * j2)];

  __shared__ float rowb[192], colb[192];
#pragma unroll
  for (int i2k = 0; i2k < 6; ++i2k) {
#pragma unroll
    for (int kh = 0; kh < 2; ++kh) {
      const int j2k = i2k * 2 + kh;
      for (int k2 = 0; k2 < 16; ++k2) {
        int k = i2k * 32 + kh * 16 + k2;       // pivot index
        int krow = kh * 16 + k2;               // k & 31
        if (ti == krow) {
#pragma unroll
          for (int j2 = 0; j2 < 12; ++j2) rowb[tj + 16 * j2] = a[i2k][j2];
        }
        if (tj == k2) {
#pragma unroll
          for (int i2 = 0; i2 < 6; ++i2) colb[ti + 32 * i2] = a[i2][j2k];
        }
        __syncthreads();
        float p = 1.0f / rowb[k];
        float rv[12];
#pragma unroll
        for (int j2 = 0; j2 < 12; ++j2) rv[j2] = rowb[tj + 16 * j2] * p;
        float cvl[6];
#pragma unroll
        for (int i2 = 0; i2 < 6; ++i2) cvl[i2] = colb[ti + 32 * i2];
#pragma unroll
        for (int i2 = 0; i2 < 6; ++i2)
#pragma unroll
          for (int j2 = 0; j2 < 12; ++j2)
            a[i2][j2] = fmaf(-cvl[i2], rv[j2], a[i2][j2]);
        if (ti == krow) {
#pragma unroll
          for (int j2 = 0; j2 < 12; ++j2) a[i2k][j2] = rv[j2];
        }
        if (tj == k2) {
#pragma unroll
          for (int i2 = 0; i2 < 6; ++i2) a[i2][j2k] = -cvl[i2] * p;
        }
        if (ti == krow && tj == k2) a[i2k][j2k] = p;
        __syncthreads();
      }
    }
  }
#pragma unroll
  for (int i2 = 0; i2 < 6; ++i2)
#pragma unroll
    for (int j2 = 0; j2 < 12; ++j2)
      O[(ti + 32 * i2) * M_ + (tj + 16 * j2)] = a[i2][j2];
}

// ---------------- fp32 tiled GEMM (Schur chain, 192-sized) ----------------
__global__ __launch_bounds__(256) void k_sgemm(
    const float* __restrict__ A, int lda, int tA, int sAg,
    const float* __restrict__ B, int ldb, int tB, int sBg,
    const float* __restrict__ Cin, int sCing, float beta,
    float alpha,
    float* __restrict__ Cout, int ldc, int sCg,
    float* __restrict__ CoutT, int ldt, int sTg,
    int M, int N, int K) {
  int g = blockIdx.z;
  A += (size_t)g * sAg;
  B += (size_t)g * sBg;
  if (Cin) Cin += (size_t)g * sCing;
  Cout += (size_t)g * sCg;
  if (CoutT) CoutT += (size_t)g * sTg;

  __shared__ float As[32][33], Bs[32][33];
  int t = threadIdx.x;
  int tx = t & 15, ty = t >> 4;
  int row0 = blockIdx.y * 32, col0 = blockIdx.x * 32;
  float acc00 = 0.f, acc01 = 0.f, acc10 = 0.f, acc11 = 0.f;

  for (int kt = 0; kt < K; kt += 32) {
    for (int idx = t; idx < 1024; idx += 256) {
      int rr = idx >> 5, cc = idx & 31;
      {
        int gr = row0 + rr, gk = kt + cc;
        As[rr][cc] = tA ? A[(size_t)gk * lda + gr] : A[(size_t)gr * lda + gk];
      }
      {
        int gk = kt + rr, gc = col0 + cc;
        Bs[rr][cc] = tB ? B[(size_t)gc * ldb + gk] : B[(size_t)gk * ldb + gc];
      }
    }
    __syncthreads();
#pragma unroll
    for (int kk = 0; kk < 32; ++kk) {
      float a0 = As[ty * 2][kk], a1 = As[ty * 2 + 1][kk];
      float b0 = Bs[kk][tx * 2], b1 = Bs[kk][tx * 2 + 1];
      acc00 = fmaf(a0, b0, acc00);
      acc01 = fmaf(a0, b1, acc01);
      acc10 = fmaf(a1, b0, acc10);
      acc11 = fmaf(a1, b1, acc11);
    }
    __syncthreads();
  }
  float accs[2][2] = {{acc00, acc01}, {acc10, acc11}};
#pragma unroll
  for (int a2 = 0; a2 < 2; ++a2)
#pragma unroll
    for (int b2 = 0; b2 < 2; ++b2) {
      int gr = row0 + ty * 2 + a2, gc = col0 + tx * 2 + b2;
      float val = alpha * accs[a2][b2];
      if (Cin) val += beta * Cin[(size_t)gr * ldc + gc];
      Cout[(size_t)gr * ldc + gc] = val;
      if (CoutT) CoutT[(size_t)gc * ldt + gr] = val;
    }
}

// ---------------- fp64 tiled GEMM: Cout = alpha*op(A)*op(B) [+ I] [+ beta*Cin] ----------------
__global__ __launch_bounds__(256) void k_dgemm(
    const double* __restrict__ A, int lda, int tA, int sAg,
    const double* __restrict__ B, int ldb, int tB, int sBg,
    const double* __restrict__ Cin, int sCing, double beta,
    double alpha, int addI,
    double* __restrict__ Cout, int ldc, int sCg,
    float* __restrict__ f32out,
    int M, int N, int K) {
  int g = blockIdx.z;
  A += (size_t)g * sAg;
  B += (size_t)g * sBg;
  if (Cin) Cin += (size_t)g * sCing;
  Cout += (size_t)g * sCg;
  if (f32out) f32out += (size_t)g * sCg;

  __shared__ double As[32][33], Bs[32][33];
  int t = threadIdx.x;
  int tx = t & 15, ty = t >> 4;
  int row0 = blockIdx.y * 32, col0 = blockIdx.x * 32;
  double acc00 = 0., acc01 = 0., acc10 = 0., acc11 = 0.;

  for (int kt = 0; kt < K; kt += 32) {
    for (int idx = t; idx < 1024; idx += 256) {
      int rr = idx >> 5, cc = idx & 31;
      {
        int gr = row0 + rr, gk = kt + cc;
        As[rr][cc] = tA ? A[(size_t)gk * lda + gr] : A[(size_t)gr * lda + gk];
      }
      {
        int gk = kt + rr, gc = col0 + cc;
        Bs[rr][cc] = tB ? B[(size_t)gc * ldb + gk] : B[(size_t)gk * ldb + gc];
      }
    }
    __syncthreads();
#pragma unroll
    for (int kk = 0; kk < 32; ++kk) {
      double a0 = As[ty * 2][kk], a1 = As[ty * 2 + 1][kk];
      double b0 = Bs[kk][tx * 2], b1 = Bs[kk][tx * 2 + 1];
      acc00 = fma(a0, b0, acc00);
      acc01 = fma(a0, b1, acc01);
      acc10 = fma(a1, b0, acc10);
      acc11 = fma(a1, b1, acc11);
    }
    __syncthreads();
  }
  double accs[2][2] = {{acc00, acc01}, {acc10, acc11}};
#pragma unroll
  for (int a2 = 0; a2 < 2; ++a2)
#pragma unroll
    for (int b2 = 0; b2 < 2; ++b2) {
      int gr = row0 + ty * 2 + a2, gc = col0 + tx * 2 + b2;
      double val = alpha * accs[a2][b2];
      if (addI && gr == gc) val += 1.0;
      if (Cin) val += beta * Cin[(size_t)gr * ldc + gc];
      Cout[(size_t)gr * ldc + gc] = val;
      if (f32out) f32out[(size_t)gr * ldc + gc] = (float)val;
    }
}

// ---------------- small helpers ----------------
__global__ void k_prep_lq(const float* __restrict__ qsqrt, double* __restrict__ Lq64) {
  int idx = blockIdx.x * 256 + threadIdx.x;
  if (idx >= G_ * MM_) return;
  int col = idx % M_;
  int row = (idx / M_) % M_;
  Lq64[idx] = (col <= row) ? (double)qsqrt[idx] : 0.0;
}

// c_g = X * q_mu[:,g] in fp64, output fp32
__global__ void k_cvec64(const double* __restrict__ X, const float* __restrict__ qmu,
                         float* __restrict__ cvec) {
  int idx = blockIdx.x * 256 + threadIdx.x;
  if (idx >= G_ * M_) return;
  int m = idx % M_, g = idx / M_;
  const double* row = X + (size_t)g * MM_ + (size_t)m * M_;
  double s = 0.0;
  for (int k = 0; k < M_; ++k) s = fma(row[k], (double)qmu[k * G_ + g], s);
  cvec[idx] = (float)s;
}

// ---------------- Kx[g][xl][m] = rbf(Z[g,m], patch(x)), x = x0 + blockIdx.x ----------------
__global__ __launch_bounds__(384) void k_kuf(const float* __restrict__ xin,
                                             const float* __restrict__ Zt,
                                             const float* vptr, const float* lptr,
                                             float* __restrict__ Kx, int x0) {
  int xl = blockIdx.x;
  int x = x0 + xl;
  int g = blockIdx.y;
  int m = threadIdx.x;
  int p = x / N_, n = x % N_;
  int hp = p / WP_, wp = p % WP_;
  __shared__ float pt[L_];
  if (m < L_) {
    int q = m / C_, c = m % C_;
    int i = q / PW_, j = q % PW_;
    pt[m] = xin[n * (H_ * W_ * C_) + ((hp + i) * W_ + (wp + j)) * C_ + c];
  }
  __syncthreads();
  float s = 0.f;
  for (int l = 0; l < L_; ++l) {
    float d = Zt[(g * L_ + l) * M_ + m] - pt[l];
    s = fmaf(d, d, s);
  }
  float v = vptr[0], ls = lptr[0];
  float c2 = -0.72134752044f / (ls * ls);
  Kx[((size_t)g * CHX_ + xl) * M_ + m] = v * exp2f(s * c2);
}

// ---------------- U = Kx * S : 64x64 tile, 4x4/thread, BK=16 ----------------
// grid (M_/64, CHX_/64, G_), block 256
__global__ __launch_bounds__(256) void k_ugemm(const float* __restrict__ Kx,
                                               const float* __restrict__ S,
                                               float* __restrict__ U) {
  int g = blockIdx.z;
  int col0 = blockIdx.x * 64;   // m'
  int row0 = blockIdx.y * 64;   // x
  const float* A = Kx + (size_t)g * CHX_ * M_;
  const float* B = S + (size_t)g * MM_;
  float* Uo = U + (size_t)g * CHX_ * M_;

  __shared__ __align__(16) float As[16][68];   // As[k][row]
  __shared__ __align__(16) float Bs[16][68];   // Bs[k][col]
  int t = threadIdx.x;
  int tr = t >> 4, tc = t & 15;
  float acc[4][4];
#pragma unroll
  for (int i = 0; i < 4; ++i)
#pragma unroll
    for (int j = 0; j < 4; ++j) acc[i][j] = 0.f;

  for (int kt = 0; kt < M_; kt += 16) {
    {
      int r = t >> 2, k4 = (t & 3) * 4;
      float4 av = *(const float4*)&A[(size_t)(row0 + r) * M_ + kt + k4];
      As[k4 + 0][r] = av.x;
      As[k4 + 1][r] = av.y;
      As[k4 + 2][r] = av.z;
      As[k4 + 3][r] = av.w;
    }
    {
      int k = t >> 4, c4 = (t & 15) * 4;
      *(float4*)&Bs[k][c4] = *(const float4*)&B[(size_t)(kt + k) * M_ + col0 + c4];
    }
    __syncthreads();
#pragma unroll
    for (int k = 0; k < 16; ++k) {
      float4 av = *(const float4*)&As[k][tr * 4];
      float4 bv = *(const float4*)&Bs[k][tc * 4];
      float a4[4] = {av.x, av.y, av.z, av.w};
      float b4[4] = {bv.x, bv.y, bv.z, bv.w};
#pragma unroll
      for (int i = 0; i < 4; ++i)
#pragma unroll
        for (int j = 0; j < 4; ++j) acc[i][j] = fmaf(a4[i], b4[j], acc[i][j]);
    }
    __syncthreads();
  }
#pragma unroll
  for (int i = 0; i < 4; ++i) {
    float4 ov = {acc[i][0], acc[i][1], acc[i][2], acc[i][3]};
    *(float4*)&Uo[(size_t)(row0 + tr * 4 + i) * M_ + col0 + tc * 4] = ov;
  }
}

// ---------------- fold: one wave per x. mean = k.c ; var = v + k.u (fp64 accum) ----------------
__global__ __launch_bounds__(256) void k_fold(const float* __restrict__ Kx,
                                              const float* __restrict__ U,
                                              const float* __restrict__ cvec,
                                              const float* vptr,
                                              float* __restrict__ outp, int x0) {
  int g = blockIdx.y;
  int wv = threadIdx.x >> 6, lane = threadIdx.x & 63;
  int xl = blockIdx.x * 4 + wv;
  int x = x0 + xl;
  const float* krow = Kx + ((size_t)g * CHX_ + xl) * M_;
  const float* urow = U + ((size_t)g * CHX_ + xl) * M_;
  const float* cg = cvec + g * M_;
  double fv = 0.0, fm = 0.0;
  for (int m = lane; m < M_; m += 64) {
    double kk = (double)krow[m];
    fv = fma(kk, (double)urow[m], fv);
    fm = fma(kk, (double)cg[m], fm);
  }
#pragma unroll
  for (int off = 32; off; off >>= 1) {
    fv += __shfl_down(fv, off);
    fm += __shfl_down(fm, off);
  }
  if (lane == 0) {
    int p = x / N_, n = x % N_;
    int oidx = n * (P_ * G_) + p * G_ + g;
    outp[oidx] = (float)fm;
    outp[PN_ * G_ + oidx] = (float)((double)vptr[0] + fv);
  }
}

extern "C" void kernel_launch(void* const* d_in, const int* in_sizes, int n_in,
                              void* d_out, int out_size, void* d_ws, size_t ws_size,
                              hipStream_t stream) {
  (void)out_size; (void)ws_size;
  const float* xin = (const float*)d_in[0];
  const float* Z = (const float*)d_in[1];
  const float* qmu = (const float*)d_in[2];
  const float* qsqrt = (const float*)d_in[3];
  const float* vptr = (const float*)d_in[4];
  const float* lptr = (const float*)d_in[5];
  {
    int scalars = 0;
    for (int i = 0; i < n_in; ++i) {
      if (in_sizes[i] == N_ * H_ * W_ * C_) xin = (const float*)d_in[i];
      else if (in_sizes[i] == G_ * M_ * L_) Z = (const float*)d_in[i];
      else if (in_sizes[i] == M_ * G_) qmu = (const float*)d_in[i];
      else if (in_sizes[i] == G_ * MM_) qsqrt = (const float*)d_in[i];
      else if (in_sizes[i] == 1) {
        if (scalars == 0) vptr = (const float*)d_in[i];
        else lptr = (const float*)d_in[i];
        ++scalars;
      }
    }
  }
  float* outp = (float*)d_out;

  char* w = (char*)d_ws;
  auto alloc = [&](size_t bytes) {
    char* r = w;
    w += (bytes + 255) & ~(size_t)255;
    return r;
  };
  float* Zt     = (float*)alloc((size_t)G_ * L_ * M_ * 4);
  float* Kuu32  = (float*)alloc((size_t)G_ * MM_ * 4);
  float* Kinv32 = (float*)alloc((size_t)G_ * MM_ * 4);
  float* Ebuf   = (float*)alloc((size_t)G_ * 192 * 192 * 4);
  double* Kuu64 = (double*)alloc((size_t)G_ * MM_ * 8);
  double* Xd    = (double*)alloc((size_t)G_ * MM_ * 8);
  double* Xd2   = (double*)alloc((size_t)G_ * MM_ * 8);
  double* Rd    = (double*)alloc((size_t)G_ * MM_ * 8);
  double* Lq64  = (double*)alloc((size_t)G_ * MM_ * 8);
  double* V64   = (double*)alloc((size_t)G_ * MM_ * 8);
  float* Sf     = (float*)alloc((size_t)G_ * MM_ * 4);
  float* cvec   = (float*)alloc((size_t)G_ * M_ * 4);
  float* Kx     = (float*)alloc((size_t)G_ * CHX_ * M_ * 4);
  float* U      = (float*)alloc((size_t)G_ * CHX_ * M_ * 4);

  k_zt<<<(G_ * L_ * M_ + 255) / 256, 256, 0, stream>>>(Z, Zt);
  k_kuu64<<<(G_ * MM_ + 255) / 256, 256, 0, stream>>>(Z, vptr, lptr, Kuu64);
  k_d2f<<<(G_ * MM_ + 255) / 256, 256, 0, stream>>>(Kuu64, Kuu32, G_ * MM_);

  // ---- fp32 seed: Kinv32 via 2x2 block Schur (192+192) ----
  k_inv192<<<G_, 512, 0, stream>>>(Kuu32, Kinv32, MM_);
  k_sgemm<<<dim3(6, 6, G_), 256, 0, stream>>>(
      Kinv32, M_, 0, MM_,
      Kuu32 + 192, M_, 0, MM_,
      nullptr, 0, 0.0f, 1.0f,
      Ebuf, 192, 192 * 192, nullptr, 0, 0, 192, 192, 192);
  k_sgemm<<<dim3(6, 6, G_), 256, 0, stream>>>(
      Kuu32 + 192, M_, 1, MM_,
      Ebuf, 192, 0, 192 * 192,
      Kuu32 + 192 * M_ + 192, MM_, 1.0f, -1.0f,
      Kuu32 + 192 * M_ + 192, M_, MM_, nullptr, 0, 0, 192, 192, 192);
  k_inv192<<<G_, 512, 0, stream>>>(Kuu32 + 192 * M_ + 192, Kinv32 + 192 * M_ + 192, MM_);
  k_sgemm<<<dim3(6, 6, G_), 256, 0, stream>>>(
      Ebuf, 192, 0, 192 * 192,
      Kinv32 + 192 * M_ + 192, M_, 0, MM_,
      nullptr, 0, 0.0f, -1.0f,
      Kinv32 + 192, M_, MM_, Kinv32 + 192 * M_, M_, MM_, 192, 192, 192);
  k_sgemm<<<dim3(6, 6, G_), 256, 0, stream>>>(
      Kinv32 + 192, M_, 0, MM_,
      Ebuf, 192, 1, 192 * 192,
      Kinv32, MM_, 1.0f, -1.0f,
      Kinv32, M_, MM_, nullptr, 0, 0, 192, 192, 192);

  // ---- Newton polish in fp64, ONE step: X2 = X + X(I - Kuu X) ----
  k_f2d<<<(G_ * MM_ + 255) / 256, 256, 0, stream>>>(Kinv32, Xd, G_ * MM_);
  k_dgemm<<<dim3(12, 12, G_), 256, 0, stream>>>(
      Kuu64, M_, 0, MM_, Xd, M_, 0, MM_,
      nullptr, 0, 0.0, -1.0, 1, Rd, M_, MM_, nullptr, M_, M_, M_);
  k_dgemm<<<dim3(12, 12, G_), 256, 0, stream>>>(
      Xd, M_, 0, MM_, Rd, M_, 0, MM_,
      Xd, MM_, 1.0, 1.0, 0, Xd2, M_, MM_, nullptr, M_, M_, M_);

  // ---- S = (X Lq)(X Lq)^T - X in fp64 -> Sf fp32 ----
  k_prep_lq<<<(G_ * MM_ + 255) / 256, 256, 0, stream>>>(qsqrt, Lq64);
  k_dgemm<<<dim3(12, 12, G_), 256, 0, stream>>>(
      Xd2, M_, 0, MM_, Lq64, M_, 0, MM_,
      nullptr, 0, 0.0, 1.0, 0, V64, M_, MM_, nullptr, M_, M_, M_);
  k_dgemm<<<dim3(12, 12, G_), 256, 0, stream>>>(
      V64, M_, 0, MM_, V64, M_, 1, MM_,
      Xd2, MM_, -1.0, 1.0, 0, Rd, M_, MM_, Sf, M_, M_, M_);

  // ---- c = X q_mu ----
  k_cvec64<<<3, 256, 0, stream>>>(Xd2, qmu, cvec);

  // ---- per-chunk: K build, U = K*S (64x64 tiles), fold ----
  for (int ch = 0; ch < PN_ / CHX_; ++ch) {
    int x0 = ch * CHX_;
    k_kuf<<<dim3(CHX_, G_), 384, 0, stream>>>(xin, Zt, vptr, lptr, Kx, x0);
    k_ugemm<<<dim3(M_ / 64, CHX_ / 64, G_), 256, 0, stream>>>(Kx, Sf, U);
    k_fold<<<dim3(CHX_ / 4, G_), 256, 0, stream>>>(Kx, U, cvec, vptr, outp, x0);
  }
}

// Round 8
// 1019.027 us; speedup vs baseline: 4.9710x; 1.1537x over previous
//
#include <hip/hip_runtime.h>

#define H_ 32
#define W_ 32
#define C_ 3
#define PH_ 5
#define PW_ 5
#define HP_ 28
#define WP_ 28
#define P_ 784
#define N_ 32
#define L_ 75
#define LP_ 80            /* padded L for float4 staging */
#define G_ 2
#define M_ 384
#define MM_ (M_*M_)       /* 147456 */
#define PN_ (P_*N_)       /* 25088 */
#define CHX_ 3136         /* x-chunk (PN_/8) */
#define JITTER_ 1e-6

// accurate exp(t) for t <= 0, fp64
__device__ __forceinline__ double exp64(double t) {
  double y = t * 1.4426950408889634;
  double nn = rint(y);
  double z = (y - nn) * 0.6931471805599453;
  double e = 1.6059043836821613e-10;
  e = fma(e, z, 2.08767569878681e-9);
  e = fma(e, z, 2.505210838544172e-8);
  e = fma(e, z, 2.755731922398589e-7);
  e = fma(e, z, 2.7557319223985893e-6);
  e = fma(e, z, 2.48015873015873e-5);
  e = fma(e, z, 1.984126984126984e-4);
  e = fma(e, z, 1.3888888888888889e-3);
  e = fma(e, z, 8.333333333333333e-3);
  e = fma(e, z, 4.1666666666666664e-2);
  e = fma(e, z, 1.6666666666666666e-1);
  e = fma(e, z, 0.5);
  e = fma(e, z, 1.0);
  e = fma(e, z, 1.0);
  return ldexp(e, (int)nn);
}

// ---------------- Z transpose: Zt[(g*L+l)*M+m] = Z[(g*M+m)*L+l] ----------------
__global__ void k_zt(const float* __restrict__ Z, float* __restrict__ Zt) {
  int idx = blockIdx.x * 256 + threadIdx.x;
  if (idx >= G_ * L_ * M_) return;
  int m = idx % M_;
  int l = (idx / M_) % L_;
  int g = idx / (M_ * L_);
  Zt[idx] = Z[(g * M_ + m) * L_ + l];
}

// ---------------- znorm[g][m] = |Z_gm|^2 ----------------
__global__ void k_znorm(const float* __restrict__ Z, float* __restrict__ znorm) {
  int idx = blockIdx.x * 256 + threadIdx.x;
  if (idx >= G_ * M_) return;
  const float* zr = Z + (size_t)idx * L_;
  float s = 0.f;
  for (int l = 0; l < L_; ++l) s = fmaf(zr[l], zr[l], s);
  znorm[idx] = s;
}

// ---------------- patches: pat[x][80] (x = p*N + n), pad cols 75..79 = 0 ----------------
__global__ void k_patches(const float* __restrict__ xin, float* __restrict__ pat) {
  int idx = blockIdx.x * 256 + threadIdx.x;
  if (idx >= PN_ * LP_) return;
  int l = idx % LP_;
  int x = idx / LP_;
  if (l >= L_) { pat[idx] = 0.f; return; }
  int n = x & 31, p = x >> 5;
  int hp = p / WP_, wp = p % WP_;
  int q = l / C_, c = l % C_;
  int i = q / PW_, j = q % PW_;
  pat[idx] = xin[n * (H_ * W_ * C_) + ((hp + i) * W_ + (wp + j)) * C_ + c];
}

// ---------------- pnorm[x] = |patch_x|^2 ----------------
__global__ void k_pnorm(const float* __restrict__ pat, float* __restrict__ pnorm) {
  int x = blockIdx.x * 256 + threadIdx.x;
  if (x >= PN_) return;
  const float* pr = pat + (size_t)x * LP_;
  float s = 0.f;
  for (int l = 0; l < L_; ++l) s = fmaf(pr[l], pr[l], s);
  pnorm[x] = s;
}

// ---------------- Kuu fp64 (accurate; fp32 seed derived by cast) ----------------
__global__ void k_kuu64(const float* __restrict__ Z, const float* vptr,
                        const float* lptr, double* __restrict__ Kuu64) {
  int idx = blockIdx.x * 256 + threadIdx.x;
  if (idx >= G_ * MM_) return;
  int j = idx % M_;
  int r = (idx / M_) % M_;
  int g = idx / MM_;
  const float* zi = Z + (g * M_ + r) * L_;
  const float* zj = Z + (g * M_ + j) * L_;
  double s = 0.0;
  for (int l = 0; l < L_; ++l) {
    double d = (double)zi[l] - (double)zj[l];
    s = fma(d, d, s);
  }
  double v = (double)vptr[0], ls = (double)lptr[0];
  double val = v * exp64(-0.5 * s / (ls * ls));
  if (r == j) val += JITTER_;
  Kuu64[idx] = val;
}

__global__ void k_d2f(const double* __restrict__ in, float* __restrict__ out, int n) {
  int idx = blockIdx.x * 256 + threadIdx.x;
  if (idx < n) out[idx] = (float)in[idx];
}
__global__ void k_f2d(const float* __restrict__ in, double* __restrict__ out, int n) {
  int idx = blockIdx.x * 256 + threadIdx.x;
  if (idx < n) out[idx] = (double)in[idx];
}

// ---------------- register-resident 192x192 Gauss-Jordan inverse (SPD, fp32) ----------------
// All register-array indices compile-time (k = i2k*32 + kh*16 + k2) — no scratch spill.
__global__ __launch_bounds__(512) void k_inv192(const float* __restrict__ in,
                                                float* __restrict__ out, int gstride) {
  int g = blockIdx.x;
  const float* A = in + (size_t)g * gstride;
  float* O = out + (size_t)g * gstride;
  int t = threadIdx.x;
  int ti = t >> 4, tj = t & 15;
  float a[6][12];
#pragma unroll
  for (int i2 = 0; i2 < 6; ++i2)
#pragma unroll
    for (int j2 = 0; j2 < 12; ++j2)
      a[i2][j2] = A[(ti + 32 * i2) * M_ + (tj + 16 * j2)];

  __shared__ float rowb[192], colb[192];
#pragma unroll
  for (int i2k = 0; i2k < 6; ++i2k) {
#pragma unroll
    for (int kh = 0; kh < 2; ++kh) {
      const int j2k = i2k * 2 + kh;
      for (int k2 = 0; k2 < 16; ++k2) {
        int k = i2k * 32 + kh * 16 + k2;
        int krow = kh * 16 + k2;
        if (ti == krow) {
#pragma unroll
          for (int j2 = 0; j2 < 12; ++j2) rowb[tj + 16 * j2] = a[i2k][j2];
        }
        if (tj == k2) {
#pragma unroll
          for (int i2 = 0; i2 < 6; ++i2) colb[ti + 32 * i2] = a[i2][j2k];
        }
        __syncthreads();
        float p = 1.0f / rowb[k];
        float rv[12];
#pragma unroll
        for (int j2 = 0; j2 < 12; ++j2) rv[j2] = rowb[tj + 16 * j2] * p;
        float cvl[6];
#pragma unroll
        for (int i2 = 0; i2 < 6; ++i2) cvl[i2] = colb[ti + 32 * i2];
#pragma unroll
        for (int i2 = 0; i2 < 6; ++i2)
#pragma unroll
          for (int j2 = 0; j2 < 12; ++j2)
            a[i2][j2] = fmaf(-cvl[i2], rv[j2], a[i2][j2]);
        if (ti == krow) {
#pragma unroll
          for (int j2 = 0; j2 < 12; ++j2) a[i2k][j2] = rv[j2];
        }
        if (tj == k2) {
#pragma unroll
          for (int i2 = 0; i2 < 6; ++i2) a[i2][j2k] = -cvl[i2] * p;
        }
        if (ti == krow && tj == k2) a[i2k][j2k] = p;
        __syncthreads();
      }
    }
  }
#pragma unroll
  for (int i2 = 0; i2 < 6; ++i2)
#pragma unroll
    for (int j2 = 0; j2 < 12; ++j2)
      O[(ti + 32 * i2) * M_ + (tj + 16 * j2)] = a[i2][j2];
}

// ---------------- fp32 tiled GEMM (Schur chain) ----------------
__global__ __launch_bounds__(256) void k_sgemm(
    const float* __restrict__ A, int lda, int tA, int sAg,
    const float* __restrict__ B, int ldb, int tB, int sBg,
    const float* __restrict__ Cin, int sCing, float beta,
    float alpha, int addI,
    float* __restrict__ Cout, int ldc, int sCg,
    float* __restrict__ CoutT, int ldt, int sTg,
    int M, int N, int K) {
  int g = blockIdx.z;
  A += (size_t)g * sAg;
  B += (size_t)g * sBg;
  if (Cin) Cin += (size_t)g * sCing;
  Cout += (size_t)g * sCg;
  if (CoutT) CoutT += (size_t)g * sTg;

  __shared__ float As[32][33], Bs[32][33];
  int t = threadIdx.x;
  int tx = t & 15, ty = t >> 4;
  int row0 = blockIdx.y * 32, col0 = blockIdx.x * 32;
  float acc00 = 0.f, acc01 = 0.f, acc10 = 0.f, acc11 = 0.f;

  for (int kt = 0; kt < K; kt += 32) {
    for (int idx = t; idx < 1024; idx += 256) {
      int rr = idx >> 5, cc = idx & 31;
      {
        int gr = row0 + rr, gk = kt + cc;
        As[rr][cc] = tA ? A[(size_t)gk * lda + gr] : A[(size_t)gr * lda + gk];
      }
      {
        int gk = kt + rr, gc = col0 + cc;
        Bs[rr][cc] = tB ? B[(size_t)gc * ldb + gk] : B[(size_t)gk * ldb + gc];
      }
    }
    __syncthreads();
#pragma unroll
    for (int kk = 0; kk < 32; ++kk) {
      float a0 = As[ty * 2][kk], a1 = As[ty * 2 + 1][kk];
      float b0 = Bs[kk][tx * 2], b1 = Bs[kk][tx * 2 + 1];
      acc00 = fmaf(a0, b0, acc00);
      acc01 = fmaf(a0, b1, acc01);
      acc10 = fmaf(a1, b0, acc10);
      acc11 = fmaf(a1, b1, acc11);
    }
    __syncthreads();
  }
  float accs[2][2] = {{acc00, acc01}, {acc10, acc11}};
#pragma unroll
  for (int a2 = 0; a2 < 2; ++a2)
#pragma unroll
    for (int b2 = 0; b2 < 2; ++b2) {
      int gr = row0 + ty * 2 + a2, gc = col0 + tx * 2 + b2;
      float val = alpha * accs[a2][b2];
      if (addI && gr == gc) val += 1.0f;
      if (Cin) val += beta * Cin[(size_t)gr * ldc + gc];
      Cout[(size_t)gr * ldc + gc] = val;
      if (CoutT) CoutT[(size_t)gc * ldt + gr] = val;
    }
}

// ---------------- fp64 tiled GEMM: Cout = alpha*op(A)*op(B) [+I] [+ beta*Cin] ----------------
__global__ __launch_bounds__(256) void k_dgemm(
    const double* __restrict__ A, int lda, int tA, int sAg,
    const double* __restrict__ B, int ldb, int tB, int sBg,
    const double* __restrict__ Cin, int sCing, double beta,
    double alpha, int addI,
    double* __restrict__ Cout, int ldc, int sCg,
    float* __restrict__ f32out,
    int M, int N, int K) {
  int g = blockIdx.z;
  A += (size_t)g * sAg;
  B += (size_t)g * sBg;
  if (Cin) Cin += (size_t)g * sCing;
  Cout += (size_t)g * sCg;
  if (f32out) f32out += (size_t)g * sCg;

  __shared__ double As[32][33], Bs[32][33];
  int t = threadIdx.x;
  int tx = t & 15, ty = t >> 4;
  int row0 = blockIdx.y * 32, col0 = blockIdx.x * 32;
  double acc00 = 0., acc01 = 0., acc10 = 0., acc11 = 0.;

  for (int kt = 0; kt < K; kt += 32) {
    for (int idx = t; idx < 1024; idx += 256) {
      int rr = idx >> 5, cc = idx & 31;
      {
        int gr = row0 + rr, gk = kt + cc;
        As[rr][cc] = tA ? A[(size_t)gk * lda + gr] : A[(size_t)gr * lda + gk];
      }
      {
        int gk = kt + rr, gc = col0 + cc;
        Bs[rr][cc] = tB ? B[(size_t)gc * ldb + gk] : B[(size_t)gk * ldb + gc];
      }
    }
    __syncthreads();
#pragma unroll
    for (int kk = 0; kk < 32; ++kk) {
      double a0 = As[ty * 2][kk], a1 = As[ty * 2 + 1][kk];
      double b0 = Bs[kk][tx * 2], b1 = Bs[kk][tx * 2 + 1];
      acc00 = fma(a0, b0, acc00);
      acc01 = fma(a0, b1, acc01);
      acc10 = fma(a1, b0, acc10);
      acc11 = fma(a1, b1, acc11);
    }
    __syncthreads();
  }
  double accs[2][2] = {{acc00, acc01}, {acc10, acc11}};
#pragma unroll
  for (int a2 = 0; a2 < 2; ++a2)
#pragma unroll
    for (int b2 = 0; b2 < 2; ++b2) {
      int gr = row0 + ty * 2 + a2, gc = col0 + tx * 2 + b2;
      double val = alpha * accs[a2][b2];
      if (addI && gr == gc) val += 1.0;
      if (Cin) val += beta * Cin[(size_t)gr * ldc + gc];
      Cout[(size_t)gr * ldc + gc] = val;
      if (f32out) f32out[(size_t)gr * ldc + gc] = (float)val;
    }
}

// ---------------- small helpers ----------------
__global__ void k_prep_lq(const float* __restrict__ qsqrt, double* __restrict__ Lq64) {
  int idx = blockIdx.x * 256 + threadIdx.x;
  if (idx >= G_ * MM_) return;
  int col = idx % M_;
  int row = (idx / M_) % M_;
  Lq64[idx] = (col <= row) ? (double)qsqrt[idx] : 0.0;
}

// c_g = X * q_mu[:,g] (fp64 in, fp32 out)
__global__ void k_cvec64(const double* __restrict__ X, const float* __restrict__ qmu,
                         float* __restrict__ cvec) {
  int idx = blockIdx.x * 256 + threadIdx.x;
  if (idx >= G_ * M_) return;
  int m = idx % M_, g = idx / M_;
  const double* row = X + (size_t)g * MM_ + (size_t)m * M_;
  double s = 0.0;
  for (int k = 0; k < M_; ++k) s = fma(row[k], (double)qmu[k * G_ + g], s);
  cvec[idx] = (float)s;
}

// ---------------- output init: mean = 0, var = variance ----------------
__global__ void k_init(float* __restrict__ outp, const float* vptr) {
  int idx = blockIdx.x * 256 + threadIdx.x;
  if (idx >= PN_ * G_) return;
  outp[idx] = 0.f;
  outp[PN_ * G_ + idx] = vptr[0];
}

// ---------------- Kuf as GEMM: Kx[g][xl][m] = v*exp2((zn+pn-2*dot)*c2) ----------------
// grid (M_/64, CHX_/64, G_), block 256, 4x4/thread, K = 80 (padded)
__global__ __launch_bounds__(256) void k_kufg(const float* __restrict__ pat,
                                              const float* __restrict__ Zt,
                                              const float* __restrict__ znorm,
                                              const float* __restrict__ pnorm,
                                              const float* vptr, const float* lptr,
                                              float* __restrict__ Kx, int x0) {
  int g = blockIdx.z;
  int col0 = blockIdx.x * 64;   // m
  int row0 = blockIdx.y * 64;   // x (chunk-local)
  __shared__ __align__(16) float As[16][68];   // As[k][x]
  __shared__ __align__(16) float Bs[16][68];   // Bs[k][m]
  int t = threadIdx.x;
  int tr = t >> 4, tc = t & 15;
  float acc[4][4];
#pragma unroll
  for (int i = 0; i < 4; ++i)
#pragma unroll
    for (int j = 0; j < 4; ++j) acc[i][j] = 0.f;

  for (int kt = 0; kt < LP_; kt += 16) {
    {
      int r = t >> 2, k4 = (t & 3) * 4;
      float4 av = *(const float4*)&pat[(size_t)(x0 + row0 + r) * LP_ + kt + k4];
      As[k4 + 0][r] = av.x;
      As[k4 + 1][r] = av.y;
      As[k4 + 2][r] = av.z;
      As[k4 + 3][r] = av.w;
    }
    {
      int k = t >> 4, c4 = (t & 15) * 4;
      float4 bv = {0.f, 0.f, 0.f, 0.f};
      if (kt + k < L_)
        bv = *(const float4*)&Zt[((size_t)(g * L_ + kt + k)) * M_ + col0 + c4];
      *(float4*)&Bs[k][c4] = bv;
    }
    __syncthreads();
#pragma unroll
    for (int k = 0; k < 16; ++k) {
      float4 av = *(const float4*)&As[k][tr * 4];
      float4 bv = *(const float4*)&Bs[k][tc * 4];
      float a4[4] = {av.x, av.y, av.z, av.w};
      float b4[4] = {bv.x, bv.y, bv.z, bv.w};
#pragma unroll
      for (int i = 0; i < 4; ++i)
#pragma unroll
        for (int j = 0; j < 4; ++j) acc[i][j] = fmaf(a4[i], b4[j], acc[i][j]);
    }
    __syncthreads();
  }
  float v = vptr[0], ls = lptr[0];
  float c2 = -0.72134752044f / (ls * ls);
#pragma unroll
  for (int i = 0; i < 4; ++i) {
    int xl = row0 + tr * 4 + i;
    float pn = pnorm[x0 + xl];
    float4 ov;
    float tmp[4];
#pragma unroll
    for (int j = 0; j < 4; ++j) {
      int m = col0 + tc * 4 + j;
      float sq = znorm[g * M_ + m] + pn - 2.0f * acc[i][j];
      tmp[j] = v * exp2f(sq * c2);
    }
    ov.x = tmp[0]; ov.y = tmp[1]; ov.z = tmp[2]; ov.w = tmp[3];
    *(float4*)&Kx[((size_t)g * CHX_ + xl) * M_ + col0 + tc * 4] = ov;
  }
}

// ---------------- fused U-GEMM + fold (fp64 partial reduce, fp32 atomics) ----------------
__global__ __launch_bounds__(256) void k_ufold(const float* __restrict__ Kx,
                                               const float* __restrict__ S,
                                               const float* __restrict__ cvec,
                                               float* __restrict__ outp, int x0) {
  int g = blockIdx.z;
  int col0 = blockIdx.x * 64;   // m'
  int row0 = blockIdx.y * 64;   // x (chunk-local)
  const float* A = Kx + (size_t)g * CHX_ * M_;
  const float* B = S + (size_t)g * MM_;

  __shared__ __align__(16) float As[16][68];
  __shared__ __align__(16) float Bs[16][68];
  __shared__ float cs[64];
  int t = threadIdx.x;
  int tr = t >> 4, tc = t & 15;
  if (t < 64) cs[t] = cvec[g * M_ + col0 + t];
  float acc[4][4];
#pragma unroll
  for (int i = 0; i < 4; ++i)
#pragma unroll
    for (int j = 0; j < 4; ++j) acc[i][j] = 0.f;

  for (int kt = 0; kt < M_; kt += 16) {
    {
      int r = t >> 2, k4 = (t & 3) * 4;
      float4 av = *(const float4*)&A[(size_t)(row0 + r) * M_ + kt + k4];
      As[k4 + 0][r] = av.x;
      As[k4 + 1][r] = av.y;
      As[k4 + 2][r] = av.z;
      As[k4 + 3][r] = av.w;
    }
    {
      int k = t >> 4, c4 = (t & 15) * 4;
      *(float4*)&Bs[k][c4] = *(const float4*)&B[(size_t)(kt + k) * M_ + col0 + c4];
    }
    __syncthreads();
#pragma unroll
    for (int k = 0; k < 16; ++k) {
      float4 av = *(const float4*)&As[k][tr * 4];
      float4 bv = *(const float4*)&Bs[k][tc * 4];
      float a4[4] = {av.x, av.y, av.z, av.w};
      float b4[4] = {bv.x, bv.y, bv.z, bv.w};
#pragma unroll
      for (int i = 0; i < 4; ++i)
#pragma unroll
        for (int j = 0; j < 4; ++j) acc[i][j] = fmaf(a4[i], b4[j], acc[i][j]);
    }
    __syncthreads();
  }

  // fold: this block's contribution over cols [col0, col0+64), fp64 partials
#pragma unroll
  for (int i = 0; i < 4; ++i) {
    int xl = row0 + tr * 4 + i;
    float4 kv = *(const float4*)&A[(size_t)xl * M_ + col0 + tc * 4];
    double pv = (double)kv.x * acc[i][0] + (double)kv.y * acc[i][1] +
                (double)kv.z * acc[i][2] + (double)kv.w * acc[i][3];
    double pm = (double)kv.x * cs[tc * 4 + 0] + (double)kv.y * cs[tc * 4 + 1] +
                (double)kv.z * cs[tc * 4 + 2] + (double)kv.w * cs[tc * 4 + 3];
#pragma unroll
    for (int mk = 1; mk < 16; mk <<= 1) {
      pv += __shfl_xor(pv, mk, 16);
      pm += __shfl_xor(pm, mk, 16);
    }
    if (tc == 0) {
      int x = x0 + xl;
      int p = x >> 5, n = x & 31;
      int oidx = n * (P_ * G_) + p * G_ + g;
      atomicAdd(&outp[oidx], (float)pm);
      atomicAdd(&outp[PN_ * G_ + oidx], (float)pv);
    }
  }
}

extern "C" void kernel_launch(void* const* d_in, const int* in_sizes, int n_in,
                              void* d_out, int out_size, void* d_ws, size_t ws_size,
                              hipStream_t stream) {
  (void)out_size; (void)ws_size;
  const float* xin = (const float*)d_in[0];
  const float* Z = (const float*)d_in[1];
  const float* qmu = (const float*)d_in[2];
  const float* qsqrt = (const float*)d_in[3];
  const float* vptr = (const float*)d_in[4];
  const float* lptr = (const float*)d_in[5];
  {
    int scalars = 0;
    for (int i = 0; i < n_in; ++i) {
      if (in_sizes[i] == N_ * H_ * W_ * C_) xin = (const float*)d_in[i];
      else if (in_sizes[i] == G_ * M_ * L_) Z = (const float*)d_in[i];
      else if (in_sizes[i] == M_ * G_) qmu = (const float*)d_in[i];
      else if (in_sizes[i] == G_ * MM_) qsqrt = (const float*)d_in[i];
      else if (in_sizes[i] == 1) {
        if (scalars == 0) vptr = (const float*)d_in[i];
        else lptr = (const float*)d_in[i];
        ++scalars;
      }
    }
  }
  float* outp = (float*)d_out;

  char* w = (char*)d_ws;
  auto alloc = [&](size_t bytes) {
    char* r = w;
    w += (bytes + 255) & ~(size_t)255;
    return r;
  };
  float* Zt     = (float*)alloc((size_t)G_ * L_ * M_ * 4);
  float* znorm  = (float*)alloc((size_t)G_ * M_ * 4);
  float* pat    = (float*)alloc((size_t)PN_ * LP_ * 4);
  float* pnorm  = (float*)alloc((size_t)PN_ * 4);
  float* Kuu32  = (float*)alloc((size_t)G_ * MM_ * 4);
  float* Kinv32 = (float*)alloc((size_t)G_ * MM_ * 4);
  float* Ebuf   = (float*)alloc((size_t)G_ * 192 * 192 * 4);
  double* Kuu64 = (double*)alloc((size_t)G_ * MM_ * 8);
  double* Xd    = (double*)alloc((size_t)G_ * MM_ * 8);
  double* Xd2   = (double*)alloc((size_t)G_ * MM_ * 8);
  double* Rd    = (double*)alloc((size_t)G_ * MM_ * 8);   // Newton residual, then V
  double* Lq64  = (double*)alloc((size_t)G_ * MM_ * 8);   // Lq, then dead fp64 S out
  float* Sf     = (float*)alloc((size_t)G_ * MM_ * 4);
  float* cvec   = (float*)alloc((size_t)G_ * M_ * 4);
  float* Kx     = (float*)alloc((size_t)G_ * CHX_ * M_ * 4);

  // ---- prep ----
  k_zt<<<(G_ * L_ * M_ + 255) / 256, 256, 0, stream>>>(Z, Zt);
  k_znorm<<<(G_ * M_ + 255) / 256, 256, 0, stream>>>(Z, znorm);
  k_patches<<<(PN_ * LP_ + 255) / 256, 256, 0, stream>>>(xin, pat);
  k_pnorm<<<(PN_ + 255) / 256, 256, 0, stream>>>(pat, pnorm);
  k_kuu64<<<(G_ * MM_ + 255) / 256, 256, 0, stream>>>(Z, vptr, lptr, Kuu64);
  k_d2f<<<(G_ * MM_ + 255) / 256, 256, 0, stream>>>(Kuu64, Kuu32, G_ * MM_);
  k_init<<<(PN_ * G_ + 255) / 256, 256, 0, stream>>>(outp, vptr);

  // ---- fp32 seed: Kinv32 via 2x2 block Schur (192+192) ----
  k_inv192<<<G_, 512, 0, stream>>>(Kuu32, Kinv32, MM_);
  k_sgemm<<<dim3(6, 6, G_), 256, 0, stream>>>(
      Kinv32, M_, 0, MM_, Kuu32 + 192, M_, 0, MM_,
      nullptr, 0, 0.0f, 1.0f, 0,
      Ebuf, 192, 192 * 192, nullptr, 0, 0, 192, 192, 192);
  k_sgemm<<<dim3(6, 6, G_), 256, 0, stream>>>(
      Kuu32 + 192, M_, 1, MM_, Ebuf, 192, 0, 192 * 192,
      Kuu32 + 192 * M_ + 192, MM_, 1.0f, -1.0f, 0,
      Kuu32 + 192 * M_ + 192, M_, MM_, nullptr, 0, 0, 192, 192, 192);
  k_inv192<<<G_, 512, 0, stream>>>(Kuu32 + 192 * M_ + 192, Kinv32 + 192 * M_ + 192, MM_);
  k_sgemm<<<dim3(6, 6, G_), 256, 0, stream>>>(
      Ebuf, 192, 0, 192 * 192, Kinv32 + 192 * M_ + 192, M_, 0, MM_,
      nullptr, 0, 0.0f, -1.0f, 0,
      Kinv32 + 192, M_, MM_, Kinv32 + 192 * M_, M_, MM_, 192, 192, 192);
  k_sgemm<<<dim3(6, 6, G_), 256, 0, stream>>>(
      Kinv32 + 192, M_, 0, MM_, Ebuf, 192, 1, 192 * 192,
      Kinv32, MM_, 1.0f, -1.0f, 0,
      Kinv32, M_, MM_, nullptr, 0, 0, 192, 192, 192);

  // ---- one fp64 Newton step: X2 = X + X(I - Kuu X) ----
  k_f2d<<<(G_ * MM_ + 255) / 256, 256, 0, stream>>>(Kinv32, Xd, G_ * MM_);
  k_dgemm<<<dim3(12, 12, G_), 256, 0, stream>>>(
      Kuu64, M_, 0, MM_, Xd, M_, 0, MM_,
      nullptr, 0, 0.0, -1.0, 1, Rd, M_, MM_, nullptr, M_, M_, M_);
  k_dgemm<<<dim3(12, 12, G_), 256, 0, stream>>>(
      Xd, M_, 0, MM_, Rd, M_, 0, MM_,
      Xd, MM_, 1.0, 1.0, 0, Xd2, M_, MM_, nullptr, M_, M_, M_);

  // ---- S = (X Lq)(X Lq)^T - X in fp64 -> Sf fp32 ; c = X q_mu ----
  k_prep_lq<<<(G_ * MM_ + 255) / 256, 256, 0, stream>>>(qsqrt, Lq64);
  k_dgemm<<<dim3(12, 12, G_), 256, 0, stream>>>(
      Xd2, M_, 0, MM_, Lq64, M_, 0, MM_,
      nullptr, 0, 0.0, 1.0, 0, Rd, M_, MM_, nullptr, M_, M_, M_);   // Rd = V
  k_dgemm<<<dim3(12, 12, G_), 256, 0, stream>>>(
      Rd, M_, 0, MM_, Rd, M_, 1, MM_,
      Xd2, MM_, -1.0, 1.0, 0, Lq64, M_, MM_, Sf, M_, M_, M_);        // Sf = V V^T - X
  k_cvec64<<<(G_ * M_ + 255) / 256, 256, 0, stream>>>(Xd2, qmu, cvec);

  // ---- per-chunk: K build (GEMM-style), fused U-GEMM + fold ----
  for (int ch = 0; ch < PN_ / CHX_; ++ch) {
    int x0 = ch * CHX_;
    k_kufg<<<dim3(M_ / 64, CHX_ / 64, G_), 256, 0, stream>>>(
        pat, Zt, znorm, pnorm, vptr, lptr, Kx, x0);
    k_ufold<<<dim3(M_ / 64, CHX_ / 64, G_), 256, 0, stream>>>(
        Kx, Sf, cvec, outp, x0);
  }
}

// Round 9
// 851.888 us; speedup vs baseline: 5.9464x; 1.1962x over previous
//
#include <hip/hip_runtime.h>

#define H_ 32
#define W_ 32
#define C_ 3
#define PH_ 5
#define PW_ 5
#define HP_ 28
#define WP_ 28
#define P_ 784
#define N_ 32
#define L_ 75
#define LP_ 80            /* padded L for float4 staging */
#define G_ 2
#define M_ 384
#define MM_ (M_*M_)       /* 147456 */
#define PN_ (P_*N_)       /* 25088 */
#define JITTER_ 1e-6

// accurate exp(t) for t <= 0, fp64
__device__ __forceinline__ double exp64(double t) {
  double y = t * 1.4426950408889634;
  double nn = rint(y);
  double z = (y - nn) * 0.6931471805599453;
  double e = 1.6059043836821613e-10;
  e = fma(e, z, 2.08767569878681e-9);
  e = fma(e, z, 2.505210838544172e-8);
  e = fma(e, z, 2.755731922398589e-7);
  e = fma(e, z, 2.7557319223985893e-6);
  e = fma(e, z, 2.48015873015873e-5);
  e = fma(e, z, 1.984126984126984e-4);
  e = fma(e, z, 1.3888888888888889e-3);
  e = fma(e, z, 8.333333333333333e-3);
  e = fma(e, z, 4.1666666666666664e-2);
  e = fma(e, z, 1.6666666666666666e-1);
  e = fma(e, z, 0.5);
  e = fma(e, z, 1.0);
  e = fma(e, z, 1.0);
  return ldexp(e, (int)nn);
}

// ---------------- Z transpose ----------------
__global__ void k_zt(const float* __restrict__ Z, float* __restrict__ Zt) {
  int idx = blockIdx.x * 256 + threadIdx.x;
  if (idx >= G_ * L_ * M_) return;
  int m = idx % M_;
  int l = (idx / M_) % L_;
  int g = idx / (M_ * L_);
  Zt[idx] = Z[(g * M_ + m) * L_ + l];
}

// ---------------- znorm ----------------
__global__ void k_znorm(const float* __restrict__ Z, float* __restrict__ znorm) {
  int idx = blockIdx.x * 256 + threadIdx.x;
  if (idx >= G_ * M_) return;
  const float* zr = Z + (size_t)idx * L_;
  float s = 0.f;
  for (int l = 0; l < L_; ++l) s = fmaf(zr[l], zr[l], s);
  znorm[idx] = s;
}

// ---------------- patches: pat[x][80] ----------------
__global__ void k_patches(const float* __restrict__ xin, float* __restrict__ pat) {
  int idx = blockIdx.x * 256 + threadIdx.x;
  if (idx >= PN_ * LP_) return;
  int l = idx % LP_;
  int x = idx / LP_;
  if (l >= L_) { pat[idx] = 0.f; return; }
  int n = x & 31, p = x >> 5;
  int hp = p / WP_, wp = p % WP_;
  int q = l / C_, c = l % C_;
  int i = q / PW_, j = q % PW_;
  pat[idx] = xin[n * (H_ * W_ * C_) + ((hp + i) * W_ + (wp + j)) * C_ + c];
}

// ---------------- pnorm ----------------
__global__ void k_pnorm(const float* __restrict__ pat, float* __restrict__ pnorm) {
  int x = blockIdx.x * 256 + threadIdx.x;
  if (x >= PN_) return;
  const float* pr = pat + (size_t)x * LP_;
  float s = 0.f;
  for (int l = 0; l < L_; ++l) s = fmaf(pr[l], pr[l], s);
  pnorm[x] = s;
}

// ---------------- Kuu fp64 ----------------
__global__ void k_kuu64(const float* __restrict__ Z, const float* vptr,
                        const float* lptr, double* __restrict__ Kuu64) {
  int idx = blockIdx.x * 256 + threadIdx.x;
  if (idx >= G_ * MM_) return;
  int j = idx % M_;
  int r = (idx / M_) % M_;
  int g = idx / MM_;
  const float* zi = Z + (g * M_ + r) * L_;
  const float* zj = Z + (g * M_ + j) * L_;
  double s = 0.0;
  for (int l = 0; l < L_; ++l) {
    double d = (double)zi[l] - (double)zj[l];
    s = fma(d, d, s);
  }
  double v = (double)vptr[0], ls = (double)lptr[0];
  double val = v * exp64(-0.5 * s / (ls * ls));
  if (r == j) val += JITTER_;
  Kuu64[idx] = val;
}

__global__ void k_d2f(const double* __restrict__ in, float* __restrict__ out, int n) {
  int idx = blockIdx.x * 256 + threadIdx.x;
  if (idx < n) out[idx] = (float)in[idx];
}
__global__ void k_f2d(const float* __restrict__ in, double* __restrict__ out, int n) {
  int idx = blockIdx.x * 256 + threadIdx.x;
  if (idx < n) out[idx] = (double)in[idx];
}

// ---------------- 192x192 Gauss-Jordan inverse, 1 barrier/iter ----------------
// Register indices compile-time (k = i2k*32 + kh*16 + k2). Next pivot row/col
// staged PRE-barrier into double-buffered rowb/colb with iteration-k update
// applied in registers.
__global__ __launch_bounds__(512) void k_inv192(const float* __restrict__ in,
                                                float* __restrict__ out, int gstride) {
  int g = blockIdx.x;
  const float* A = in + (size_t)g * gstride;
  float* O = out + (size_t)g * gstride;
  int t = threadIdx.x;
  int ti = t >> 4, tj = t & 15;
  float a[6][12];
#pragma unroll
  for (int i2 = 0; i2 < 6; ++i2)
#pragma unroll
    for (int j2 = 0; j2 < 12; ++j2)
      a[i2][j2] = A[(ti + 32 * i2) * M_ + (tj + 16 * j2)];

  __shared__ float rowb[2][192], colb[2][192];
  // stage k=0
  if (ti == 0) {
#pragma unroll
    for (int j2 = 0; j2 < 12; ++j2) rowb[0][tj + 16 * j2] = a[0][j2];
  }
  if (tj == 0) {
#pragma unroll
    for (int i2 = 0; i2 < 6; ++i2) colb[0][ti + 32 * i2] = a[i2][0];
  }
  __syncthreads();

#pragma unroll
  for (int i2k = 0; i2k < 6; ++i2k) {
#pragma unroll
    for (int kh = 0; kh < 2; ++kh) {
      const int j2k = i2k * 2 + kh;
      for (int k2 = 0; k2 < 16; ++k2) {
        const int k = i2k * 32 + kh * 16 + k2;
        const int cur = k & 1, nxt = cur ^ 1;
        const int krow = kh * 16 + k2;
        float p = 1.0f / rowb[cur][k];
        float rv[12];
#pragma unroll
        for (int j2 = 0; j2 < 12; ++j2) rv[j2] = rowb[cur][tj + 16 * j2] * p;
        float cvl[6];
#pragma unroll
        for (int i2 = 0; i2 < 6; ++i2) cvl[i2] = colb[cur][ti + 32 * i2];

        // ---- stage pivot row/col k+1 (post-update values), pre-barrier ----
        if (k2 < 15) {
          // in-block: row k+1 lives at (i2k, krow+1); col k+1 at (j2k, k2+1)
          if (ti == krow + 1) {
#pragma unroll
            for (int j2 = 0; j2 < 12; ++j2) {
              float tv = fmaf(-cvl[i2k], rv[j2], a[i2k][j2]);
              if (tj == k2 && j2 == j2k) tv = -cvl[i2k] * p;   // element (k+1, k)
              rowb[nxt][tj + 16 * j2] = tv;
            }
          }
          if (tj == k2 + 1) {
#pragma unroll
            for (int i2 = 0; i2 < 6; ++i2) {
              float tv = fmaf(-cvl[i2], rv[j2k], a[i2][j2k]);
              if (ti == krow && i2 == i2k) tv = rv[j2k];       // element (k, k+1)
              colb[nxt][ti + 32 * i2] = tv;
            }
          }
        } else if (!(i2k == 5 && kh == 1)) {
          // boundary: k+1 starts next 16-block
          const int i2k1 = (kh == 0) ? i2k : i2k + 1;
          const int krow1 = (kh == 0) ? 16 : 0;
          const int j2k1 = j2k + 1;
          if (ti == krow1) {
#pragma unroll
            for (int j2 = 0; j2 < 12; ++j2) {
              float tv = fmaf(-cvl[i2k1], rv[j2], a[i2k1][j2]);
              if (tj == 15 && j2 == j2k) tv = -cvl[i2k1] * p;  // element (k+1, k)
              rowb[nxt][tj + 16 * j2] = tv;
            }
          }
          if (tj == 0) {
#pragma unroll
            for (int i2 = 0; i2 < 6; ++i2) {
              float tv = fmaf(-cvl[i2], rv[j2k1], a[i2][j2k1]);
              if (ti == krow && i2 == i2k) tv = rv[j2k1];      // element (k, k+1)
              colb[nxt][ti + 32 * i2] = tv;
            }
          }
        }
        __syncthreads();

        // ---- uniform update + pivot specials ----
#pragma unroll
        for (int i2 = 0; i2 < 6; ++i2)
#pragma unroll
          for (int j2 = 0; j2 < 12; ++j2)
            a[i2][j2] = fmaf(-cvl[i2], rv[j2], a[i2][j2]);
        if (ti == krow) {
#pragma unroll
          for (int j2 = 0; j2 < 12; ++j2) a[i2k][j2] = rv[j2];
        }
        if (tj == k2) {
#pragma unroll
          for (int i2 = 0; i2 < 6; ++i2) a[i2][j2k] = -cvl[i2] * p;
        }
        if (ti == krow && tj == k2) a[i2k][j2k] = p;
      }
    }
  }
#pragma unroll
  for (int i2 = 0; i2 < 6; ++i2)
#pragma unroll
    for (int j2 = 0; j2 < 12; ++j2)
      O[(ti + 32 * i2) * M_ + (tj + 16 * j2)] = a[i2][j2];
}

// ---------------- fp32 tiled GEMM (Schur chain) ----------------
__global__ __launch_bounds__(256) void k_sgemm(
    const float* __restrict__ A, int lda, int tA, int sAg,
    const float* __restrict__ B, int ldb, int tB, int sBg,
    const float* __restrict__ Cin, int sCing, float beta,
    float alpha, int addI,
    float* __restrict__ Cout, int ldc, int sCg,
    float* __restrict__ CoutT, int ldt, int sTg,
    int M, int N, int K) {
  int g = blockIdx.z;
  A += (size_t)g * sAg;
  B += (size_t)g * sBg;
  if (Cin) Cin += (size_t)g * sCing;
  Cout += (size_t)g * sCg;
  if (CoutT) CoutT += (size_t)g * sTg;

  __shared__ float As[32][33], Bs[32][33];
  int t = threadIdx.x;
  int tx = t & 15, ty = t >> 4;
  int row0 = blockIdx.y * 32, col0 = blockIdx.x * 32;
  float acc00 = 0.f, acc01 = 0.f, acc10 = 0.f, acc11 = 0.f;

  for (int kt = 0; kt < K; kt += 32) {
    for (int idx = t; idx < 1024; idx += 256) {
      int rr = idx >> 5, cc = idx & 31;
      {
        int gr = row0 + rr, gk = kt + cc;
        As[rr][cc] = tA ? A[(size_t)gk * lda + gr] : A[(size_t)gr * lda + gk];
      }
      {
        int gk = kt + rr, gc = col0 + cc;
        Bs[rr][cc] = tB ? B[(size_t)gc * ldb + gk] : B[(size_t)gk * ldb + gc];
      }
    }
    __syncthreads();
#pragma unroll
    for (int kk = 0; kk < 32; ++kk) {
      float a0 = As[ty * 2][kk], a1 = As[ty * 2 + 1][kk];
      float b0 = Bs[kk][tx * 2], b1 = Bs[kk][tx * 2 + 1];
      acc00 = fmaf(a0, b0, acc00);
      acc01 = fmaf(a0, b1, acc01);
      acc10 = fmaf(a1, b0, acc10);
      acc11 = fmaf(a1, b1, acc11);
    }
    __syncthreads();
  }
  float accs[2][2] = {{acc00, acc01}, {acc10, acc11}};
#pragma unroll
  for (int a2 = 0; a2 < 2; ++a2)
#pragma unroll
    for (int b2 = 0; b2 < 2; ++b2) {
      int gr = row0 + ty * 2 + a2, gc = col0 + tx * 2 + b2;
      float val = alpha * accs[a2][b2];
      if (addI && gr == gc) val += 1.0f;
      if (Cin) val += beta * Cin[(size_t)gr * ldc + gc];
      Cout[(size_t)gr * ldc + gc] = val;
      if (CoutT) CoutT[(size_t)gc * ldt + gr] = val;
    }
}

// ---------------- fp64 tiled GEMM ----------------
__global__ __launch_bounds__(256) void k_dgemm(
    const double* __restrict__ A, int lda, int tA, int sAg,
    const double* __restrict__ B, int ldb, int tB, int sBg,
    const double* __restrict__ Cin, int sCing, double beta,
    double alpha, int addI,
    double* __restrict__ Cout, int ldc, int sCg,
    float* __restrict__ f32out,
    int M, int N, int K) {
  int g = blockIdx.z;
  A += (size_t)g * sAg;
  B += (size_t)g * sBg;
  if (Cin) Cin += (size_t)g * sCing;
  Cout += (size_t)g * sCg;
  if (f32out) f32out += (size_t)g * sCg;

  __shared__ double As[32][33], Bs[32][33];
  int t = threadIdx.x;
  int tx = t & 15, ty = t >> 4;
  int row0 = blockIdx.y * 32, col0 = blockIdx.x * 32;
  double acc00 = 0., acc01 = 0., acc10 = 0., acc11 = 0.;

  for (int kt = 0; kt < K; kt += 32) {
    for (int idx = t; idx < 1024; idx += 256) {
      int rr = idx >> 5, cc = idx & 31;
      {
        int gr = row0 + rr, gk = kt + cc;
        As[rr][cc] = tA ? A[(size_t)gk * lda + gr] : A[(size_t)gr * lda + gk];
      }
      {
        int gk = kt + rr, gc = col0 + cc;
        Bs[rr][cc] = tB ? B[(size_t)gc * ldb + gk] : B[(size_t)gk * ldb + gc];
      }
    }
    __syncthreads();
#pragma unroll
    for (int kk = 0; kk < 32; ++kk) {
      double a0 = As[ty * 2][kk], a1 = As[ty * 2 + 1][kk];
      double b0 = Bs[kk][tx * 2], b1 = Bs[kk][tx * 2 + 1];
      acc00 = fma(a0, b0, acc00);
      acc01 = fma(a0, b1, acc01);
      acc10 = fma(a1, b0, acc10);
      acc11 = fma(a1, b1, acc11);
    }
    __syncthreads();
  }
  double accs[2][2] = {{acc00, acc01}, {acc10, acc11}};
#pragma unroll
  for (int a2 = 0; a2 < 2; ++a2)
#pragma unroll
    for (int b2 = 0; b2 < 2; ++b2) {
      int gr = row0 + ty * 2 + a2, gc = col0 + tx * 2 + b2;
      double val = alpha * accs[a2][b2];
      if (addI && gr == gc) val += 1.0;
      if (Cin) val += beta * Cin[(size_t)gr * ldc + gc];
      Cout[(size_t)gr * ldc + gc] = val;
      if (f32out) f32out[(size_t)gr * ldc + gc] = (float)val;
    }
}

// ---------------- small helpers ----------------
__global__ void k_prep_lq(const float* __restrict__ qsqrt, double* __restrict__ Lq64) {
  int idx = blockIdx.x * 256 + threadIdx.x;
  if (idx >= G_ * MM_) return;
  int col = idx % M_;
  int row = (idx / M_) % M_;
  Lq64[idx] = (col <= row) ? (double)qsqrt[idx] : 0.0;
}

__global__ void k_cvec64(const double* __restrict__ X, const float* __restrict__ qmu,
                         float* __restrict__ cvec) {
  int idx = blockIdx.x * 256 + threadIdx.x;
  if (idx >= G_ * M_) return;
  int m = idx % M_, g = idx / M_;
  const double* row = X + (size_t)g * MM_ + (size_t)m * M_;
  double s = 0.0;
  for (int k = 0; k < M_; ++k) s = fma(row[k], (double)qmu[k * G_ + g], s);
  cvec[idx] = (float)s;
}

__global__ void k_init(float* __restrict__ outp, const float* vptr) {
  int idx = blockIdx.x * 256 + threadIdx.x;
  if (idx >= PN_ * G_) return;
  outp[idx] = 0.f;
  outp[PN_ * G_ + idx] = vptr[0];
}

// ---------------- Kuf as GEMM (64x64 tile, runtime chunk) ----------------
__global__ __launch_bounds__(256) void k_kufg(const float* __restrict__ pat,
                                              const float* __restrict__ Zt,
                                              const float* __restrict__ znorm,
                                              const float* __restrict__ pnorm,
                                              const float* vptr, const float* lptr,
                                              float* __restrict__ Kx, int x0, int chx) {
  int g = blockIdx.z;
  int col0 = blockIdx.x * 64;
  int row0 = blockIdx.y * 64;
  __shared__ __align__(16) float As[16][68];
  __shared__ __align__(16) float Bs[16][68];
  int t = threadIdx.x;
  int tr = t >> 4, tc = t & 15;
  float acc[4][4] = {};

  for (int kt = 0; kt < LP_; kt += 16) {
    {
      int r = t >> 2, k4 = (t & 3) * 4;
      float4 av = *(const float4*)&pat[(size_t)(x0 + row0 + r) * LP_ + kt + k4];
      As[k4 + 0][r] = av.x;
      As[k4 + 1][r] = av.y;
      As[k4 + 2][r] = av.z;
      As[k4 + 3][r] = av.w;
    }
    {
      int k = t >> 4, c4 = (t & 15) * 4;
      float4 bv = {0.f, 0.f, 0.f, 0.f};
      if (kt + k < L_)
        bv = *(const float4*)&Zt[((size_t)(g * L_ + kt + k)) * M_ + col0 + c4];
      *(float4*)&Bs[k][c4] = bv;
    }
    __syncthreads();
#pragma unroll
    for (int k = 0; k < 16; ++k) {
      float4 av = *(const float4*)&As[k][tr * 4];
      float4 bv = *(const float4*)&Bs[k][tc * 4];
      float a4[4] = {av.x, av.y, av.z, av.w};
      float b4[4] = {bv.x, bv.y, bv.z, bv.w};
#pragma unroll
      for (int i = 0; i < 4; ++i)
#pragma unroll
        for (int j = 0; j < 4; ++j) acc[i][j] = fmaf(a4[i], b4[j], acc[i][j]);
    }
    __syncthreads();
  }
  float v = vptr[0], ls = lptr[0];
  float c2 = -0.72134752044f / (ls * ls);
#pragma unroll
  for (int i = 0; i < 4; ++i) {
    int xl = row0 + tr * 4 + i;
    float pn = pnorm[x0 + xl];
    float4 ov;
    float tmp[4];
#pragma unroll
    for (int j = 0; j < 4; ++j) {
      int m = col0 + tc * 4 + j;
      float sq = znorm[g * M_ + m] + pn - 2.0f * acc[i][j];
      tmp[j] = v * exp2f(sq * c2);
    }
    ov.x = tmp[0]; ov.y = tmp[1]; ov.z = tmp[2]; ov.w = tmp[3];
    *(float4*)&Kx[((size_t)g * chx + xl) * M_ + col0 + tc * 4] = ov;
  }
}

// ---------------- fused U-GEMM + fold, 128x128 tile, 8x8/thread ----------------
// col mapping per thread: j<4 -> col0 + tc*4 + j ; j>=4 -> col0 + 64 + tc*4 + (j-4)
__global__ __launch_bounds__(256) void k_ufold(const float* __restrict__ Kx,
                                               const float* __restrict__ S,
                                               const float* __restrict__ cvec,
                                               float* __restrict__ outp,
                                               int x0, int chx) {
  int g = blockIdx.z;
  int col0 = blockIdx.x * 128;
  int row0 = blockIdx.y * 128;
  const float* A = Kx + (size_t)g * chx * M_;
  const float* B = S + (size_t)g * MM_;

  __shared__ __align__(16) float As[16][132];
  __shared__ __align__(16) float Bs[16][132];
  __shared__ float cs[128];
  int t = threadIdx.x;
  int tr = t >> 4, tc = t & 15;
  if (t < 128) cs[t] = cvec[g * M_ + col0 + t];
  float acc[8][8] = {};

  for (int kt = 0; kt < M_; kt += 16) {
    {
      int r = t >> 1, kbase = (t & 1) * 8;
      const float* src = &A[(size_t)(row0 + r) * M_ + kt + kbase];
      float4 a0 = *(const float4*)src;
      float4 a1 = *(const float4*)(src + 4);
      As[kbase + 0][r] = a0.x; As[kbase + 1][r] = a0.y;
      As[kbase + 2][r] = a0.z; As[kbase + 3][r] = a0.w;
      As[kbase + 4][r] = a1.x; As[kbase + 5][r] = a1.y;
      As[kbase + 6][r] = a1.z; As[kbase + 7][r] = a1.w;
    }
    {
      int k = t >> 4;
      int c1 = (t & 15) * 4, c2 = c1 + 64;
      *(float4*)&Bs[k][c1] = *(const float4*)&B[(size_t)(kt + k) * M_ + col0 + c1];
      *(float4*)&Bs[k][c2] = *(const float4*)&B[(size_t)(kt + k) * M_ + col0 + c2];
    }
    __syncthreads();
#pragma unroll
    for (int k = 0; k < 16; ++k) {
      float4 av0 = *(const float4*)&As[k][tr * 8];
      float4 av1 = *(const float4*)&As[k][tr * 8 + 4];
      float4 bv0 = *(const float4*)&Bs[k][tc * 4];
      float4 bv1 = *(const float4*)&Bs[k][64 + tc * 4];
      float a8[8] = {av0.x, av0.y, av0.z, av0.w, av1.x, av1.y, av1.z, av1.w};
      float b8[8] = {bv0.x, bv0.y, bv0.z, bv0.w, bv1.x, bv1.y, bv1.z, bv1.w};
#pragma unroll
      for (int i = 0; i < 8; ++i)
#pragma unroll
        for (int j = 0; j < 8; ++j) acc[i][j] = fmaf(a8[i], b8[j], acc[i][j]);
    }
    __syncthreads();
  }

  // fold: partial var/mean over this block's 128 cols, fp64 partials
#pragma unroll
  for (int i = 0; i < 8; ++i) {
    int xl = row0 + tr * 8 + i;
    const float* arow = &A[(size_t)xl * M_ + col0];
    float4 kv0 = *(const float4*)&arow[tc * 4];
    float4 kv1 = *(const float4*)&arow[64 + tc * 4];
    float k8[8] = {kv0.x, kv0.y, kv0.z, kv0.w, kv1.x, kv1.y, kv1.z, kv1.w};
    double pv = 0.0, pm = 0.0;
#pragma unroll
    for (int j = 0; j < 4; ++j) {
      pv += (double)k8[j] * acc[i][j];
      pm += (double)k8[j] * cs[tc * 4 + j];
    }
#pragma unroll
    for (int j = 4; j < 8; ++j) {
      pv += (double)k8[j] * acc[i][j];
      pm += (double)k8[j] * cs[64 + tc * 4 + (j - 4)];
    }
#pragma unroll
    for (int mk = 1; mk < 16; mk <<= 1) {
      pv += __shfl_xor(pv, mk, 16);
      pm += __shfl_xor(pm, mk, 16);
    }
    if (tc == 0) {
      int x = x0 + xl;
      int p = x >> 5, n = x & 31;
      int oidx = n * (P_ * G_) + p * G_ + g;
      atomicAdd(&outp[oidx], (float)pm);
      atomicAdd(&outp[PN_ * G_ + oidx], (float)pv);
    }
  }
}

extern "C" void kernel_launch(void* const* d_in, const int* in_sizes, int n_in,
                              void* d_out, int out_size, void* d_ws, size_t ws_size,
                              hipStream_t stream) {
  (void)out_size;
  const float* xin = (const float*)d_in[0];
  const float* Z = (const float*)d_in[1];
  const float* qmu = (const float*)d_in[2];
  const float* qsqrt = (const float*)d_in[3];
  const float* vptr = (const float*)d_in[4];
  const float* lptr = (const float*)d_in[5];
  {
    int scalars = 0;
    for (int i = 0; i < n_in; ++i) {
      if (in_sizes[i] == N_ * H_ * W_ * C_) xin = (const float*)d_in[i];
      else if (in_sizes[i] == G_ * M_ * L_) Z = (const float*)d_in[i];
      else if (in_sizes[i] == M_ * G_) qmu = (const float*)d_in[i];
      else if (in_sizes[i] == G_ * MM_) qsqrt = (const float*)d_in[i];
      else if (in_sizes[i] == 1) {
        if (scalars == 0) vptr = (const float*)d_in[i];
        else lptr = (const float*)d_in[i];
        ++scalars;
      }
    }
  }
  float* outp = (float*)d_out;

  auto align256 = [](size_t b) { return (b + 255) & ~(size_t)255; };
  // fixed workspace demand
  size_t fixed = 0;
  fixed += align256((size_t)G_ * L_ * M_ * 4);      // Zt
  fixed += align256((size_t)G_ * M_ * 4);           // znorm
  fixed += align256((size_t)PN_ * LP_ * 4);         // pat
  fixed += align256((size_t)PN_ * 4);               // pnorm
  fixed += align256((size_t)G_ * MM_ * 4) * 2;      // Kuu32, Kinv32
  fixed += align256((size_t)G_ * 192 * 192 * 4);    // Ebuf
  fixed += align256((size_t)G_ * MM_ * 8) * 5;      // Kuu64, Xd, Xd2, Rd, Lq64
  fixed += align256((size_t)G_ * MM_ * 4);          // Sf
  fixed += align256((size_t)G_ * M_ * 4);           // cvec
  size_t kxfull = (size_t)G_ * PN_ * M_ * 4;
  int nc = 4;
  if (ws_size >= fixed + align256(kxfull) + (1u << 20)) nc = 1;
  else if (ws_size >= fixed + align256(kxfull / 2) + (1u << 20)) nc = 2;
  int chx = PN_ / nc;   // 25088 / {1,2,4} — all divisible by 128

  char* w = (char*)d_ws;
  auto alloc = [&](size_t bytes) {
    char* r = w;
    w += (bytes + 255) & ~(size_t)255;
    return r;
  };
  float* Zt     = (float*)alloc((size_t)G_ * L_ * M_ * 4);
  float* znorm  = (float*)alloc((size_t)G_ * M_ * 4);
  float* pat    = (float*)alloc((size_t)PN_ * LP_ * 4);
  float* pnorm  = (float*)alloc((size_t)PN_ * 4);
  float* Kuu32  = (float*)alloc((size_t)G_ * MM_ * 4);
  float* Kinv32 = (float*)alloc((size_t)G_ * MM_ * 4);
  float* Ebuf   = (float*)alloc((size_t)G_ * 192 * 192 * 4);
  double* Kuu64 = (double*)alloc((size_t)G_ * MM_ * 8);
  double* Xd    = (double*)alloc((size_t)G_ * MM_ * 8);
  double* Xd2   = (double*)alloc((size_t)G_ * MM_ * 8);
  double* Rd    = (double*)alloc((size_t)G_ * MM_ * 8);
  double* Lq64  = (double*)alloc((size_t)G_ * MM_ * 8);
  float* Sf     = (float*)alloc((size_t)G_ * MM_ * 4);
  float* cvec   = (float*)alloc((size_t)G_ * M_ * 4);
  float* Kx     = (float*)alloc((size_t)G_ * chx * M_ * 4);

  // ---- prep ----
  k_zt<<<(G_ * L_ * M_ + 255) / 256, 256, 0, stream>>>(Z, Zt);
  k_znorm<<<(G_ * M_ + 255) / 256, 256, 0, stream>>>(Z, znorm);
  k_patches<<<(PN_ * LP_ + 255) / 256, 256, 0, stream>>>(xin, pat);
  k_pnorm<<<(PN_ + 255) / 256, 256, 0, stream>>>(pat, pnorm);
  k_kuu64<<<(G_ * MM_ + 255) / 256, 256, 0, stream>>>(Z, vptr, lptr, Kuu64);
  k_d2f<<<(G_ * MM_ + 255) / 256, 256, 0, stream>>>(Kuu64, Kuu32, G_ * MM_);
  k_init<<<(PN_ * G_ + 255) / 256, 256, 0, stream>>>(outp, vptr);

  // ---- fp32 seed: Kinv32 via 2x2 block Schur (192+192) ----
  k_inv192<<<G_, 512, 0, stream>>>(Kuu32, Kinv32, MM_);
  k_sgemm<<<dim3(6, 6, G_), 256, 0, stream>>>(
      Kinv32, M_, 0, MM_, Kuu32 + 192, M_, 0, MM_,
      nullptr, 0, 0.0f, 1.0f, 0,
      Ebuf, 192, 192 * 192, nullptr, 0, 0, 192, 192, 192);
  k_sgemm<<<dim3(6, 6, G_), 256, 0, stream>>>(
      Kuu32 + 192, M_, 1, MM_, Ebuf, 192, 0, 192 * 192,
      Kuu32 + 192 * M_ + 192, MM_, 1.0f, -1.0f, 0,
      Kuu32 + 192 * M_ + 192, M_, MM_, nullptr, 0, 0, 192, 192, 192);
  k_inv192<<<G_, 512, 0, stream>>>(Kuu32 + 192 * M_ + 192, Kinv32 + 192 * M_ + 192, MM_);
  k_sgemm<<<dim3(6, 6, G_), 256, 0, stream>>>(
      Ebuf, 192, 0, 192 * 192, Kinv32 + 192 * M_ + 192, M_, 0, MM_,
      nullptr, 0, 0.0f, -1.0f, 0,
      Kinv32 + 192, M_, MM_, Kinv32 + 192 * M_, M_, MM_, 192, 192, 192);
  k_sgemm<<<dim3(6, 6, G_), 256, 0, stream>>>(
      Kinv32 + 192, M_, 0, MM_, Ebuf, 192, 1, 192 * 192,
      Kinv32, MM_, 1.0f, -1.0f, 0,
      Kinv32, M_, MM_, nullptr, 0, 0, 192, 192, 192);

  // ---- one fp64 Newton step: X2 = X + X(I - Kuu X) ----
  k_f2d<<<(G_ * MM_ + 255) / 256, 256, 0, stream>>>(Kinv32, Xd, G_ * MM_);
  k_dgemm<<<dim3(12, 12, G_), 256, 0, stream>>>(
      Kuu64, M_, 0, MM_, Xd, M_, 0, MM_,
      nullptr, 0, 0.0, -1.0, 1, Rd, M_, MM_, nullptr, M_, M_, M_);
  k_dgemm<<<dim3(12, 12, G_), 256, 0, stream>>>(
      Xd, M_, 0, MM_, Rd, M_, 0, MM_,
      Xd, MM_, 1.0, 1.0, 0, Xd2, M_, MM_, nullptr, M_, M_, M_);

  // ---- S = (X Lq)(X Lq)^T - X in fp64 -> Sf fp32 ; c = X q_mu ----
  k_prep_lq<<<(G_ * MM_ + 255) / 256, 256, 0, stream>>>(qsqrt, Lq64);
  k_dgemm<<<dim3(12, 12, G_), 256, 0, stream>>>(
      Xd2, M_, 0, MM_, Lq64, M_, 0, MM_,
      nullptr, 0, 0.0, 1.0, 0, Rd, M_, MM_, nullptr, M_, M_, M_);   // Rd = V
  k_dgemm<<<dim3(12, 12, G_), 256, 0, stream>>>(
      Rd, M_, 0, MM_, Rd, M_, 1, MM_,
      Xd2, MM_, -1.0, 1.0, 0, Lq64, M_, MM_, Sf, M_, M_, M_);        // Sf = V V^T - X
  k_cvec64<<<(G_ * M_ + 255) / 256, 256, 0, stream>>>(Xd2, qmu, cvec);

  // ---- per-chunk: K build, fused U-GEMM + fold ----
  for (int ch = 0; ch < nc; ++ch) {
    int x0 = ch * chx;
    k_kufg<<<dim3(M_ / 64, chx / 64, G_), 256, 0, stream>>>(
        pat, Zt, znorm, pnorm, vptr, lptr, Kx, x0, chx);
    k_ufold<<<dim3(M_ / 128, chx / 128, G_), 256, 0, stream>>>(
        Kx, Sf, cvec, outp, x0, chx);
  }
}